// Round 2
// baseline (747.364 us; speedup 1.0000x reference)
//
#include <hip/hip_runtime.h>

typedef __attribute__((ext_vector_type(8))) short bf16x8;
typedef __attribute__((ext_vector_type(4))) float f32x4;
typedef unsigned short u16;

constexpr int B_   = 16;
constexpr int C_   = 256;
constexpr int NH   = 8;
constexpr int DH   = 64;
constexpr int NMEM = 4;
constexpr int HID  = 512;    // NH*DH
constexpr int QKVC = 1536;   // 3*HID
constexpr int N_   = 4096;   // 64*64

__device__ __forceinline__ u16 f2b(float f) {   // RNE f32->bf16
  union { float f; unsigned u; } v{f};
  unsigned r = v.u + 0x7fff + ((v.u >> 16) & 1);
  return (u16)(r >> 16);
}
__device__ __forceinline__ float b2f(u16 h) {
  union { unsigned u; float f; } v; v.u = ((unsigned)h) << 16; return v.f;
}

// ---------------- weights -> bf16 (once per call) ----------------
__global__ void k_cvtw(const float* __restrict__ wq, const float* __restrict__ wo,
                       u16* __restrict__ wqb, u16* __restrict__ wob) {
  int i = blockIdx.x * 256 + threadIdx.x;
  for (int idx = i; idx < QKVC * C_; idx += gridDim.x * 256) wqb[idx] = f2b(wq[idx]);
  for (int idx = i; idx < C_ * HID; idx += gridDim.x * 256) wob[idx] = f2b(wo[idx]);
}

// ---------------- rmsnorm1 + transpose to bf16 [g][n][c] ----------------
__global__ __launch_bounds__(256) void k_rms1(const float* __restrict__ x,
                                              const float* __restrict__ g1,
                                              u16* __restrict__ xbT) {
  int g = blockIdx.y;
  int n = blockIdx.x * 256 + threadIdx.x;
  const float* xp = x + (size_t)g * C_ * N_ + n;
  float ss = 0.f;
  #pragma unroll 8
  for (int c = 0; c < C_; ++c) { float v = xp[(size_t)c * N_]; ss += v * v; }
  float inv = 16.0f / fmaxf(sqrtf(ss), 1e-12f);
  u16* op = xbT + ((size_t)g * N_ + n) * C_;
  for (int c0 = 0; c0 < C_; c0 += 8) {
    union { bf16x8 v; u16 u[8]; } pk;
    #pragma unroll
    for (int j = 0; j < 8; ++j) pk.u[j] = f2b(xp[(size_t)(c0 + j) * N_] * inv * g1[c0 + j]);
    *(bf16x8*)(op + c0) = pk.v;
  }
}

// ---------------- QKV GEMM: qkv[g][o][n] = sum_c W[o][c]*Xn[c][n], bf16 MFMA ----------------
__global__ __launch_bounds__(256) void k_qkv(const u16* __restrict__ Wb,
                                             const u16* __restrict__ XT,
                                             u16* __restrict__ qkv) {
  constexpr int BM = 128, BN = 128, BK = 32;
  __shared__ __align__(16) u16 As[BM * BK];
  __shared__ __align__(16) u16 Bs[BN * BK];
  int g  = blockIdx.z;
  int o0 = blockIdx.x * BM;
  int n0 = blockIdx.y * BN;
  int t = threadIdx.x, wave = t >> 6, lane = t & 63;
  int wm = wave >> 1, wn = wave & 1;     // 2x2 wave grid, 64x64 per wave
  int kg = lane >> 4, lr = lane & 15;

  const u16* Ag = Wb + (size_t)o0 * C_;
  const u16* Bg = XT + ((size_t)g * N_ + n0) * C_;

  f32x4 acc[4][4];
  #pragma unroll
  for (int i = 0; i < 4; ++i)
    #pragma unroll
    for (int j = 0; j < 4; ++j) acc[i][j] = (f32x4)0.f;

  for (int k0 = 0; k0 < C_; k0 += BK) {
    #pragma unroll
    for (int i = 0; i < 2; ++i) {
      int id = t + 256 * i;
      int r = id >> 2, ch = id & 3;     // 128 rows x 4 16B-chunks
      *(bf16x8*)(As + r * 32 + ((ch ^ (r & 3)) * 8)) = *(const bf16x8*)(Ag + (size_t)r * C_ + k0 + ch * 8);
      *(bf16x8*)(Bs + r * 32 + ((ch ^ (r & 3)) * 8)) = *(const bf16x8*)(Bg + (size_t)r * C_ + k0 + ch * 8);
    }
    __syncthreads();
    bf16x8 a[4], bv[4];
    #pragma unroll
    for (int mf = 0; mf < 4; ++mf) {
      int r = wm * 64 + mf * 16 + lr;
      a[mf] = *(const bf16x8*)(As + r * 32 + ((kg ^ (r & 3)) * 8));
    }
    #pragma unroll
    for (int nf = 0; nf < 4; ++nf) {
      int r = wn * 64 + nf * 16 + lr;
      bv[nf] = *(const bf16x8*)(Bs + r * 32 + ((kg ^ (r & 3)) * 8));
    }
    #pragma unroll
    for (int mf = 0; mf < 4; ++mf)
      #pragma unroll
      for (int nf = 0; nf < 4; ++nf)
        acc[mf][nf] = __builtin_amdgcn_mfma_f32_16x16x32_bf16(a[mf], bv[nf], acc[mf][nf], 0, 0, 0);
    __syncthreads();
  }
  u16* Og = qkv + (size_t)g * QKVC * N_;
  #pragma unroll
  for (int mf = 0; mf < 4; ++mf)
    #pragma unroll
    for (int nf = 0; nf < 4; ++nf)
      #pragma unroll
      for (int j = 0; j < 4; ++j) {
        int row = o0 + wm * 64 + mf * 16 + kg * 4 + j;
        int col = n0 + wn * 64 + nf * 16 + lr;
        Og[(size_t)row * N_ + col] = f2b(acc[mf][nf][j]);
      }
}

// ---------------- k-softmax stats: one wave per (g,h,d) ----------------
__global__ __launch_bounds__(256) void k_kstat(const u16* __restrict__ qkv,
                                               const float* __restrict__ memkv,
                                               float* __restrict__ kst) {
  int g = blockIdx.z, h = blockIdx.y;
  int t = threadIdx.x, wave = t >> 6, lane = t & 63;
  int d = blockIdx.x * 4 + wave;
  const u16* row = qkv + ((size_t)g * QKVC + HID + h * DH + d) * N_;
  const float* mk = memkv + ((size_t)h * DH + d) * NMEM;
  float m = -1e30f;
  #pragma unroll
  for (int cc = 0; cc < 8; ++cc) {
    union { bf16x8 v; u16 u[8]; } pk;
    pk.v = *(const bf16x8*)(row + (cc * 64 + lane) * 8);
    #pragma unroll
    for (int j = 0; j < 8; ++j) m = fmaxf(m, b2f(pk.u[j]));
  }
  #pragma unroll
  for (int off = 32; off > 0; off >>= 1) m = fmaxf(m, __shfl_xor(m, off));
  #pragma unroll
  for (int j = 0; j < NMEM; ++j) m = fmaxf(m, mk[j]);
  float s = 0.f;
  #pragma unroll
  for (int cc = 0; cc < 8; ++cc) {
    union { bf16x8 v; u16 u[8]; } pk;
    pk.v = *(const bf16x8*)(row + (cc * 64 + lane) * 8);
    #pragma unroll
    for (int j = 0; j < 8; ++j) s += __expf(b2f(pk.u[j]) - m);
  }
  #pragma unroll
  for (int off = 32; off > 0; off >>= 1) s += __shfl_xor(s, off);
  if (lane == 0) {
    #pragma unroll
    for (int j = 0; j < NMEM; ++j) s += __expf(mk[j] - m);
    float* o = kst + ((size_t)(g * NH + h) * DH + d) * 2;
    o[0] = m; o[1] = s;
  }
}

// ---------------- context partials over an n-chunk of 1024 ----------------
__global__ __launch_bounds__(256) void k_ctx2(const u16* __restrict__ qkv,
                                              const float* __restrict__ memkv,
                                              const float* __restrict__ kst,
                                              float* __restrict__ ctxp) {
  int g = blockIdx.z, h = blockIdx.y, nc = blockIdx.x;
  int t = threadIdx.x;
  __shared__ float kb[64][65];
  __shared__ float vb[64][65];
  int d = t >> 2, e0 = (t & 3) * 16;
  const u16* Kg = qkv + ((size_t)g * QKVC + HID + h * DH) * N_;
  const u16* Vg = qkv + ((size_t)g * QKVC + 2 * HID + h * DH) * N_;
  float md = kst[((size_t)(g * NH + h) * DH + d) * 2];
  float acc[16];
  #pragma unroll
  for (int j = 0; j < 16; ++j) acc[j] = 0.f;

  for (int it = 0; it < 16; ++it) {
    int n0 = nc * 1024 + it * 64;
    #pragma unroll
    for (int i = 0; i < 2; ++i) {
      int id = t + 256 * i;            // 0..511
      int r = id >> 3, cc = (id & 7) * 8;
      union { bf16x8 v; u16 u[8]; } pk, pv2;
      pk.v  = *(const bf16x8*)(Kg + (size_t)r * N_ + n0 + cc);
      pv2.v = *(const bf16x8*)(Vg + (size_t)r * N_ + n0 + cc);
      #pragma unroll
      for (int j = 0; j < 8; ++j) { kb[r][cc + j] = b2f(pk.u[j]); vb[r][cc + j] = b2f(pv2.u[j]); }
    }
    __syncthreads();
    #pragma unroll 4
    for (int nn = 0; nn < 64; ++nn) {
      float p = __expf(kb[d][nn] - md);
      #pragma unroll
      for (int j = 0; j < 16; ++j) acc[j] += p * vb[e0 + j][nn];
    }
    __syncthreads();
  }
  if (nc == 0) {
    const float* mk = memkv + (size_t)h * DH * NMEM;
    const float* mv = memkv + (size_t)(NH + h) * DH * NMEM;
    #pragma unroll
    for (int j = 0; j < NMEM; ++j) {
      float p = __expf(mk[d * NMEM + j] - md);
      #pragma unroll
      for (int q = 0; q < 16; ++q) acc[q] += p * mv[(e0 + q) * NMEM + j];
    }
  }
  float* cg = ctxp + (((size_t)(g * NH + h) * 4) + nc) * (DH * DH) + d * DH + e0;
  #pragma unroll
  for (int j = 0; j < 16; ++j) cg[j] = acc[j];
}

// ---------------- q-softmax + PV -> attnT[g][n][hid] bf16 ----------------
__global__ __launch_bounds__(256) void k_pv(const u16* __restrict__ qkv,
                                            const float* __restrict__ ctxp,
                                            const float* __restrict__ kst,
                                            u16* __restrict__ attnT) {
  int g = blockIdx.z, h = blockIdx.y;
  int t = threadIdx.x;
  int n = blockIdx.x * 256 + t;
  __shared__ float cs[DH * DH];
  const float* cp = ctxp + (size_t)(g * NH + h) * 4 * (DH * DH);
  const float* ks = kst + (size_t)(g * NH + h) * DH * 2;
  #pragma unroll
  for (int i = 0; i < 16; ++i) {
    int idx = t + 256 * i;
    float s = ks[(idx >> 6) * 2 + 1];
    cs[idx] = (cp[idx] + cp[idx + 4096] + cp[idx + 8192] + cp[idx + 12288]) / s;
  }
  __syncthreads();

  const u16* Qg = qkv + ((size_t)g * QKVC + (size_t)h * DH) * N_ + n;
  float q[64];
  float m = -1e30f;
  #pragma unroll
  for (int d = 0; d < DH; ++d) { q[d] = b2f(Qg[(size_t)d * N_]); m = fmaxf(m, q[d]); }
  float s = 0.f;
  #pragma unroll
  for (int d = 0; d < DH; ++d) { q[d] = __expf(q[d] - m); s += q[d]; }
  float inv = 0.125f / s;
  #pragma unroll
  for (int d = 0; d < DH; ++d) q[d] *= inv;

  u16* op = attnT + ((size_t)g * N_ + n) * HID + h * DH;
  for (int e0 = 0; e0 < DH; e0 += 8) {
    union { bf16x8 v; u16 u[8]; } pk;
    #pragma unroll
    for (int j = 0; j < 8; ++j) {
      int e = e0 + j;
      float a0 = 0, a1 = 0, a2 = 0, a3 = 0;
      #pragma unroll
      for (int d = 0; d < DH; d += 4) {
        a0 += cs[d * DH + e] * q[d];
        a1 += cs[(d + 1) * DH + e] * q[d + 1];
        a2 += cs[(d + 2) * DH + e] * q[d + 2];
        a3 += cs[(d + 3) * DH + e] * q[d + 3];
      }
      pk.u[j] = f2b((a0 + a1) + (a2 + a3));
    }
    *(bf16x8*)(op + e0) = pk.v;
  }
}

// ---------------- out-proj GEMM + bias + fused rmsnorm2 ----------------
__global__ __launch_bounds__(256) void k_out(const u16* __restrict__ Wb,
                                             const u16* __restrict__ AT,
                                             const float* __restrict__ bias,
                                             const float* __restrict__ g2,
                                             float* __restrict__ out) {
  constexpr int BN = 64, BK = 32;
  __shared__ __align__(16) u16 As[256 * BK];   // 16KB
  __shared__ __align__(16) u16 Bs[BN * BK];    // 4KB
  __shared__ float part[4][BN];
  int g  = blockIdx.y;
  int n0 = blockIdx.x * BN;
  int t = threadIdx.x, wave = t >> 6, lane = t & 63;
  int kg = lane >> 4, lr = lane & 15;

  const u16* Bg = AT + ((size_t)g * N_ + n0) * HID;

  f32x4 acc[4][4];
  #pragma unroll
  for (int i = 0; i < 4; ++i)
    #pragma unroll
    for (int j = 0; j < 4; ++j) acc[i][j] = (f32x4)0.f;

  for (int k0 = 0; k0 < HID; k0 += BK) {
    #pragma unroll
    for (int i = 0; i < 4; ++i) {
      int id = t + 256 * i;
      int r = id >> 2, ch = id & 3;      // 256 rows x 4 chunks
      *(bf16x8*)(As + r * 32 + ((ch ^ (r & 3)) * 8)) = *(const bf16x8*)(Wb + (size_t)r * HID + k0 + ch * 8);
    }
    {
      int r = t >> 2, ch = t & 3;        // 64 rows x 4 chunks
      *(bf16x8*)(Bs + r * 32 + ((ch ^ (r & 3)) * 8)) = *(const bf16x8*)(Bg + (size_t)r * HID + k0 + ch * 8);
    }
    __syncthreads();
    bf16x8 a[4], bv[4];
    #pragma unroll
    for (int mf = 0; mf < 4; ++mf) {
      int r = wave * 64 + mf * 16 + lr;
      a[mf] = *(const bf16x8*)(As + r * 32 + ((kg ^ (r & 3)) * 8));
    }
    #pragma unroll
    for (int nf = 0; nf < 4; ++nf) {
      int r = nf * 16 + lr;
      bv[nf] = *(const bf16x8*)(Bs + r * 32 + ((kg ^ (r & 3)) * 8));
    }
    #pragma unroll
    for (int mf = 0; mf < 4; ++mf)
      #pragma unroll
      for (int nf = 0; nf < 4; ++nf)
        acc[mf][nf] = __builtin_amdgcn_mfma_f32_16x16x32_bf16(a[mf], bv[nf], acc[mf][nf], 0, 0, 0);
    __syncthreads();
  }
  // epilogue: bias, per-column sumsq (over all 256 rows), rmsnorm, store f32
  float colsq[4] = {0.f, 0.f, 0.f, 0.f};
  #pragma unroll
  for (int mf = 0; mf < 4; ++mf)
    #pragma unroll
    for (int j = 0; j < 4; ++j) {
      int row = wave * 64 + mf * 16 + kg * 4 + j;
      float bs = bias[row];
      #pragma unroll
      for (int nf = 0; nf < 4; ++nf) {
        float v = acc[mf][nf][j] + bs;
        acc[mf][nf][j] = v;
        colsq[nf] += v * v;
      }
    }
  #pragma unroll
  for (int nf = 0; nf < 4; ++nf) {
    colsq[nf] += __shfl_xor(colsq[nf], 16);
    colsq[nf] += __shfl_xor(colsq[nf], 32);
  }
  if (kg == 0) {
    #pragma unroll
    for (int nf = 0; nf < 4; ++nf) part[wave][nf * 16 + lr] = colsq[nf];
  }
  __syncthreads();
  float* og = out + (size_t)g * C_ * N_ + n0;
  #pragma unroll
  for (int nf = 0; nf < 4; ++nf) {
    int col = nf * 16 + lr;
    float tot = part[0][col] + part[1][col] + part[2][col] + part[3][col];
    float invn = 16.0f / fmaxf(sqrtf(tot), 1e-12f);
    #pragma unroll
    for (int mf = 0; mf < 4; ++mf)
      #pragma unroll
      for (int j = 0; j < 4; ++j) {
        int row = wave * 64 + mf * 16 + kg * 4 + j;
        og[(size_t)row * N_ + col] = acc[mf][nf][j] * invn * g2[row];
      }
  }
}

extern "C" void kernel_launch(void* const* d_in, const int* in_sizes, int n_in,
                              void* d_out, int out_size, void* d_ws, size_t ws_size,
                              hipStream_t stream) {
  (void)in_sizes; (void)n_in; (void)out_size;
  const float* x      = (const float*)d_in[0];
  const float* gain1  = (const float*)d_in[1];
  const float* w_qkv  = (const float*)d_in[2];
  const float* mem_kv = (const float*)d_in[3];
  const float* w_out  = (const float*)d_in[4];
  const float* b_out  = (const float*)d_in[5];
  const float* gain2  = (const float*)d_in[6];
  float* out = (float*)d_out;

  char* ws = (char*)d_ws;
  // shared (weights) region
  u16* wqkvb = (u16*)ws;                         // 786,432 B
  u16* woutb = (u16*)(ws + 786432);              // 262,144 B
  size_t shared_b = 1048576;

  // per-batch chunk buffers
  const size_t xbT_b   = (size_t)N_ * C_ * 2;          //  2 MiB
  const size_t qkv_b   = (size_t)QKVC * N_ * 2;        // 12 MiB
  const size_t attnT_b = (size_t)HID * N_ * 2;         //  4 MiB
  const size_t ctxp_b  = (size_t)NH * 4 * DH * DH * 4; // 512 KiB
  const size_t kst_b   = (size_t)NH * DH * 2 * 4;      //   4 KiB
  const size_t per_b   = xbT_b + qkv_b + attnT_b + ctxp_b + kst_b;

  int G = 16;
  while (G > 1 && shared_b + (size_t)G * per_b > ws_size) G >>= 1;

  char* base = ws + shared_b;
  u16*   xbT   = (u16*)base;
  u16*   qkv   = (u16*)(base + (size_t)G * xbT_b);
  u16*   attnT = (u16*)(base + (size_t)G * (xbT_b + qkv_b));
  float* ctxp  = (float*)(base + (size_t)G * (xbT_b + qkv_b + attnT_b));
  float* kst   = (float*)(base + (size_t)G * (xbT_b + qkv_b + attnT_b + ctxp_b));

  k_cvtw<<<256, 256, 0, stream>>>(w_qkv, w_out, wqkvb, woutb);

  for (int b0 = 0; b0 < B_; b0 += G) {
    const float* xc = x + (size_t)b0 * C_ * N_;
    float*       oc = out + (size_t)b0 * C_ * N_;
    k_rms1 <<<dim3(N_ / 256, G),      256, 0, stream>>>(xc, gain1, xbT);
    k_qkv  <<<dim3(QKVC / 128, N_ / 128, G), 256, 0, stream>>>(wqkvb, xbT, qkv);
    k_kstat<<<dim3(DH / 4, NH, G),    256, 0, stream>>>(qkv, mem_kv, kst);
    k_ctx2 <<<dim3(4, NH, G),         256, 0, stream>>>(qkv, mem_kv, kst, ctxp);
    k_pv   <<<dim3(N_ / 256, NH, G),  256, 0, stream>>>(qkv, ctxp, kst, attnT);
    k_out  <<<dim3(N_ / 64, G),       256, 0, stream>>>(woutb, attnT, b_out, gain2, oc);
  }
}

// Round 3
// 396.411 us; speedup vs baseline: 1.8853x; 1.8853x over previous
//
#include <hip/hip_runtime.h>

typedef __attribute__((ext_vector_type(8))) short bf16x8;
typedef __attribute__((ext_vector_type(4))) float f32x4;
typedef unsigned short u16;

constexpr int B_   = 16;
constexpr int C_   = 256;
constexpr int NH   = 8;
constexpr int DH   = 64;
constexpr int NMEM = 4;
constexpr int HID  = 512;    // NH*DH
constexpr int QKVC = 1536;   // 3*HID
constexpr int N_   = 4096;   // 64*64

__device__ __forceinline__ u16 f2b(float f) {   // RNE f32->bf16
  union { float f; unsigned u; } v{f};
  unsigned r = v.u + 0x7fff + ((v.u >> 16) & 1);
  return (u16)(r >> 16);
}
__device__ __forceinline__ float b2f(u16 h) {
  union { unsigned u; float f; } v; v.u = ((unsigned)h) << 16; return v.f;
}

// ---------------- weights -> bf16 (once per call) ----------------
__global__ void k_cvtw(const float* __restrict__ wq, const float* __restrict__ wo,
                       u16* __restrict__ wqb, u16* __restrict__ wob) {
  int i = blockIdx.x * 256 + threadIdx.x;
  for (int idx = i; idx < QKVC * C_; idx += gridDim.x * 256) wqb[idx] = f2b(wq[idx]);
  for (int idx = i; idx < C_ * HID; idx += gridDim.x * 256) wob[idx] = f2b(wo[idx]);
}

// ---------------- rmsnorm1 + transpose to bf16 [g][n][c] ----------------
__global__ __launch_bounds__(256) void k_rms1(const float* __restrict__ x,
                                              const float* __restrict__ g1,
                                              u16* __restrict__ xbT) {
  int g = blockIdx.y;
  int n = blockIdx.x * 256 + threadIdx.x;
  const float* xp = x + (size_t)g * C_ * N_ + n;
  float ss = 0.f;
  #pragma unroll 8
  for (int c = 0; c < C_; ++c) { float v = xp[(size_t)c * N_]; ss += v * v; }
  float inv = 16.0f / fmaxf(sqrtf(ss), 1e-12f);
  u16* op = xbT + ((size_t)g * N_ + n) * C_;
  for (int c0 = 0; c0 < C_; c0 += 8) {
    union { bf16x8 v; u16 u[8]; } pk;
    #pragma unroll
    for (int j = 0; j < 8; ++j) pk.u[j] = f2b(xp[(size_t)(c0 + j) * N_] * inv * g1[c0 + j]);
    *(bf16x8*)(op + c0) = pk.v;
  }
}

// ---------------- QKV GEMM: qkv[g][o][n] = sum_c W[o][c]*Xn[c][n], bf16 MFMA ----------------
__global__ __launch_bounds__(256) void k_qkv(const u16* __restrict__ Wb,
                                             const u16* __restrict__ XT,
                                             u16* __restrict__ qkv) {
  constexpr int BM = 128, BN = 128, BK = 32;
  __shared__ __align__(16) u16 As[BM * BK];
  __shared__ __align__(16) u16 Bs[BN * BK];
  int g  = blockIdx.z;
  int o0 = blockIdx.x * BM;
  int n0 = blockIdx.y * BN;
  int t = threadIdx.x, wave = t >> 6, lane = t & 63;
  int wm = wave >> 1, wn = wave & 1;     // 2x2 wave grid, 64x64 per wave
  int kg = lane >> 4, lr = lane & 15;

  const u16* Ag = Wb + (size_t)o0 * C_;
  const u16* Bg = XT + ((size_t)g * N_ + n0) * C_;

  f32x4 acc[4][4];
  #pragma unroll
  for (int i = 0; i < 4; ++i)
    #pragma unroll
    for (int j = 0; j < 4; ++j) acc[i][j] = (f32x4)0.f;

  for (int k0 = 0; k0 < C_; k0 += BK) {
    #pragma unroll
    for (int i = 0; i < 2; ++i) {
      int id = t + 256 * i;
      int r = id >> 2, ch = id & 3;     // 128 rows x 4 16B-chunks
      *(bf16x8*)(As + r * 32 + ((ch ^ (r & 3)) * 8)) = *(const bf16x8*)(Ag + (size_t)r * C_ + k0 + ch * 8);
      *(bf16x8*)(Bs + r * 32 + ((ch ^ (r & 3)) * 8)) = *(const bf16x8*)(Bg + (size_t)r * C_ + k0 + ch * 8);
    }
    __syncthreads();
    bf16x8 a[4], bv[4];
    #pragma unroll
    for (int mf = 0; mf < 4; ++mf) {
      int r = wm * 64 + mf * 16 + lr;
      a[mf] = *(const bf16x8*)(As + r * 32 + ((kg ^ (r & 3)) * 8));
    }
    #pragma unroll
    for (int nf = 0; nf < 4; ++nf) {
      int r = wn * 64 + nf * 16 + lr;
      bv[nf] = *(const bf16x8*)(Bs + r * 32 + ((kg ^ (r & 3)) * 8));
    }
    #pragma unroll
    for (int mf = 0; mf < 4; ++mf)
      #pragma unroll
      for (int nf = 0; nf < 4; ++nf)
        acc[mf][nf] = __builtin_amdgcn_mfma_f32_16x16x32_bf16(a[mf], bv[nf], acc[mf][nf], 0, 0, 0);
    __syncthreads();
  }
  u16* Og = qkv + (size_t)g * QKVC * N_;
  #pragma unroll
  for (int mf = 0; mf < 4; ++mf)
    #pragma unroll
    for (int nf = 0; nf < 4; ++nf)
      #pragma unroll
      for (int j = 0; j < 4; ++j) {
        int row = o0 + wm * 64 + mf * 16 + kg * 4 + j;
        int col = n0 + wn * 64 + nf * 16 + lr;
        Og[(size_t)row * N_ + col] = f2b(acc[mf][nf][j]);
      }
}

// ---------------- context partials via MFMA: P=exp(K), C_p[d][e] = sum_n P[d][n] V[e][n] ----------------
// grid (8 n-chunks of 512, NH, G). Each wave owns 16 d-rows. Also emits P row-sums.
__global__ __launch_bounds__(256) void k_ctx2(const u16* __restrict__ qkv,
                                              float* __restrict__ ctxp) {
  constexpr int TK = 128;                       // n per staging tile
  __shared__ __align__(16) u16 Pl[64 * TK];     // 16KB, swizzled
  __shared__ __align__(16) u16 Vl[64 * TK];     // 16KB, swizzled
  int g = blockIdx.z, h = blockIdx.y, nc = blockIdx.x;
  int t = threadIdx.x, wave = t >> 6, lane = t & 63;
  int kg = lane >> 4, lr = lane & 15;
  const u16* Kg = qkv + ((size_t)g * QKVC + HID + h * DH) * N_;
  const u16* Vg = qkv + ((size_t)g * QKVC + 2 * HID + h * DH) * N_;

  f32x4 acc[4];
  #pragma unroll
  for (int nf = 0; nf < 4; ++nf) acc[nf] = (f32x4)0.f;
  float rsum[4] = {0.f, 0.f, 0.f, 0.f};

  for (int it = 0; it < 4; ++it) {
    int n0 = nc * 512 + it * TK;
    #pragma unroll
    for (int s = 0; s < 4; ++s) {
      int cid = t + 256 * s;
      int r = cid >> 4, cc = cid & 15;          // 64 rows x 16 chunks of 8
      union { bf16x8 v; u16 u[8]; } kv_, vv, pw;
      kv_.v = *(const bf16x8*)(Kg + (size_t)r * N_ + n0 + cc * 8);
      vv.v  = *(const bf16x8*)(Vg + (size_t)r * N_ + n0 + cc * 8);
      #pragma unroll
      for (int j = 0; j < 8; ++j) {
        float p = __expf(b2f(kv_.u[j]));
        rsum[s] += p;
        pw.u[j] = f2b(p);
      }
      *(bf16x8*)(Pl + r * TK + ((cc ^ (r & 15)) * 8)) = pw.v;
      *(bf16x8*)(Vl + r * TK + ((cc ^ (r & 15)) * 8)) = vv.v;
    }
    __syncthreads();
    #pragma unroll
    for (int k = 0; k < 4; ++k) {
      int c = k * 4 + kg;
      bf16x8 af = *(const bf16x8*)(Pl + (wave * 16 + lr) * TK + ((c ^ lr) * 8));
      #pragma unroll
      for (int nf = 0; nf < 4; ++nf) {
        bf16x8 bfv = *(const bf16x8*)(Vl + (nf * 16 + lr) * TK + ((c ^ lr) * 8));
        acc[nf] = __builtin_amdgcn_mfma_f32_16x16x32_bf16(af, bfv, acc[nf], 0, 0, 0);
      }
    }
    __syncthreads();
  }
  float* cgp = ctxp + ((size_t)(g * NH + h) * 8 + nc) * 4160;
  #pragma unroll
  for (int nf = 0; nf < 4; ++nf)
    #pragma unroll
    for (int j = 0; j < 4; ++j) {
      int d = wave * 16 + kg * 4 + j;
      int e = nf * 16 + lr;
      cgp[d * 64 + e] = acc[nf][j];
    }
  // P row-sums: row = wave*4 + kg + 16*s, 16 lanes (lr) hold partials
  #pragma unroll
  for (int s = 0; s < 4; ++s) {
    #pragma unroll
    for (int m = 1; m < 16; m <<= 1) rsum[s] += __shfl_xor(rsum[s], m);
  }
  if (lr == 0) {
    #pragma unroll
    for (int s = 0; s < 4; ++s) cgp[4096 + (wave * 4 + kg + 16 * s)] = rsum[s];
  }
}

// ---------------- finalize context: sum partials + mem terms, / s_d ----------------
__global__ __launch_bounds__(256) void k_cfin(const float* __restrict__ ctxp,
                                              const float* __restrict__ memkv,
                                              float* __restrict__ ctxf) {
  int g = blockIdx.y, h = blockIdx.x;
  int t = threadIdx.x;
  __shared__ float emk[DH * NMEM];
  __shared__ float sd[DH];
  const float* mk = memkv + (size_t)h * DH * NMEM;
  const float* mv = memkv + (size_t)(NH + h) * DH * NMEM;
  const float* cp = ctxp + (size_t)(g * NH + h) * 8 * 4160;
  emk[t] = __expf(mk[t]);                      // t = d*4+j
  __syncthreads();
  if (t < DH) {
    float s = 0.f;
    #pragma unroll
    for (int p = 0; p < 8; ++p) s += cp[p * 4160 + 4096 + t];
    #pragma unroll
    for (int j = 0; j < NMEM; ++j) s += emk[t * 4 + j];
    sd[t] = s;
  }
  __syncthreads();
  float* cf = ctxf + (size_t)(g * NH + h) * 4096;
  #pragma unroll
  for (int i = 0; i < 16; ++i) {
    int idx = t + 256 * i;
    int d = idx >> 6, e = idx & 63;
    float v = 0.f;
    #pragma unroll
    for (int p = 0; p < 8; ++p) v += cp[p * 4160 + idx];
    #pragma unroll
    for (int j = 0; j < NMEM; ++j) v += emk[d * 4 + j] * mv[e * 4 + j];
    cf[idx] = v / sd[d];
  }
}

// ---------------- q-softmax + PV -> attnT[g][n][hid] bf16 ----------------
__global__ __launch_bounds__(256) void k_pv(const u16* __restrict__ qkv,
                                            const float* __restrict__ ctxf,
                                            u16* __restrict__ attnT) {
  int g = blockIdx.z, h = blockIdx.y;
  int t = threadIdx.x;
  int n = blockIdx.x * 256 + t;
  __shared__ float cs[DH * DH];
  const float* cf = ctxf + (size_t)(g * NH + h) * 4096;
  #pragma unroll
  for (int i = 0; i < 16; ++i) cs[t + 256 * i] = cf[t + 256 * i];
  __syncthreads();

  const u16* Qg = qkv + ((size_t)g * QKVC + (size_t)h * DH) * N_ + n;
  float q[64];
  float s = 0.f;
  #pragma unroll
  for (int d = 0; d < DH; ++d) { q[d] = __expf(b2f(Qg[(size_t)d * N_])); s += q[d]; }
  float inv = 0.125f / s;
  #pragma unroll
  for (int d = 0; d < DH; ++d) q[d] *= inv;

  u16* op = attnT + ((size_t)g * N_ + n) * HID + h * DH;
  for (int e0 = 0; e0 < DH; e0 += 8) {
    union { bf16x8 v; u16 u[8]; } pk;
    #pragma unroll
    for (int j = 0; j < 8; ++j) {
      int e = e0 + j;
      float a0 = 0, a1 = 0, a2 = 0, a3 = 0;
      #pragma unroll
      for (int d = 0; d < DH; d += 4) {
        a0 += cs[d * DH + e] * q[d];
        a1 += cs[(d + 1) * DH + e] * q[d + 1];
        a2 += cs[(d + 2) * DH + e] * q[d + 2];
        a3 += cs[(d + 3) * DH + e] * q[d + 3];
      }
      pk.u[j] = f2b((a0 + a1) + (a2 + a3));
    }
    *(bf16x8*)(op + e0) = pk.v;
  }
}

// ---------------- out-proj GEMM + bias + fused rmsnorm2 ----------------
__global__ __launch_bounds__(256) void k_out(const u16* __restrict__ Wb,
                                             const u16* __restrict__ AT,
                                             const float* __restrict__ bias,
                                             const float* __restrict__ g2,
                                             float* __restrict__ out) {
  constexpr int BN = 64, BK = 32;
  __shared__ __align__(16) u16 As[256 * BK];   // 16KB
  __shared__ __align__(16) u16 Bs[BN * BK];    // 4KB
  __shared__ float part[4][BN];
  int g  = blockIdx.y;
  int n0 = blockIdx.x * BN;
  int t = threadIdx.x, wave = t >> 6, lane = t & 63;
  int kg = lane >> 4, lr = lane & 15;

  const u16* Bg = AT + ((size_t)g * N_ + n0) * HID;

  f32x4 acc[4][4];
  #pragma unroll
  for (int i = 0; i < 4; ++i)
    #pragma unroll
    for (int j = 0; j < 4; ++j) acc[i][j] = (f32x4)0.f;

  for (int k0 = 0; k0 < HID; k0 += BK) {
    #pragma unroll
    for (int i = 0; i < 4; ++i) {
      int id = t + 256 * i;
      int r = id >> 2, ch = id & 3;      // 256 rows x 4 chunks
      *(bf16x8*)(As + r * 32 + ((ch ^ (r & 3)) * 8)) = *(const bf16x8*)(Wb + (size_t)r * HID + k0 + ch * 8);
    }
    {
      int r = t >> 2, ch = t & 3;        // 64 rows x 4 chunks
      *(bf16x8*)(Bs + r * 32 + ((ch ^ (r & 3)) * 8)) = *(const bf16x8*)(Bg + (size_t)r * HID + k0 + ch * 8);
    }
    __syncthreads();
    bf16x8 a[4], bv[4];
    #pragma unroll
    for (int mf = 0; mf < 4; ++mf) {
      int r = wave * 64 + mf * 16 + lr;
      a[mf] = *(const bf16x8*)(As + r * 32 + ((kg ^ (r & 3)) * 8));
    }
    #pragma unroll
    for (int nf = 0; nf < 4; ++nf) {
      int r = nf * 16 + lr;
      bv[nf] = *(const bf16x8*)(Bs + r * 32 + ((kg ^ (r & 3)) * 8));
    }
    #pragma unroll
    for (int mf = 0; mf < 4; ++mf)
      #pragma unroll
      for (int nf = 0; nf < 4; ++nf)
        acc[mf][nf] = __builtin_amdgcn_mfma_f32_16x16x32_bf16(a[mf], bv[nf], acc[mf][nf], 0, 0, 0);
    __syncthreads();
  }
  // epilogue: bias, per-column sumsq (over all 256 rows), rmsnorm, store f32
  float colsq[4] = {0.f, 0.f, 0.f, 0.f};
  #pragma unroll
  for (int mf = 0; mf < 4; ++mf)
    #pragma unroll
    for (int j = 0; j < 4; ++j) {
      int row = wave * 64 + mf * 16 + kg * 4 + j;
      float bs = bias[row];
      #pragma unroll
      for (int nf = 0; nf < 4; ++nf) {
        float v = acc[mf][nf][j] + bs;
        acc[mf][nf][j] = v;
        colsq[nf] += v * v;
      }
    }
  #pragma unroll
  for (int nf = 0; nf < 4; ++nf) {
    colsq[nf] += __shfl_xor(colsq[nf], 16);
    colsq[nf] += __shfl_xor(colsq[nf], 32);
  }
  if (kg == 0) {
    #pragma unroll
    for (int nf = 0; nf < 4; ++nf) part[wave][nf * 16 + lr] = colsq[nf];
  }
  __syncthreads();
  float* og = out + (size_t)g * C_ * N_ + n0;
  #pragma unroll
  for (int nf = 0; nf < 4; ++nf) {
    int col = nf * 16 + lr;
    float tot = part[0][col] + part[1][col] + part[2][col] + part[3][col];
    float invn = 16.0f / fmaxf(sqrtf(tot), 1e-12f);
    #pragma unroll
    for (int mf = 0; mf < 4; ++mf)
      #pragma unroll
      for (int j = 0; j < 4; ++j) {
        int row = wave * 64 + mf * 16 + kg * 4 + j;
        og[(size_t)row * N_ + col] = acc[mf][nf][j] * invn * g2[row];
      }
  }
}

extern "C" void kernel_launch(void* const* d_in, const int* in_sizes, int n_in,
                              void* d_out, int out_size, void* d_ws, size_t ws_size,
                              hipStream_t stream) {
  (void)in_sizes; (void)n_in; (void)out_size;
  const float* x      = (const float*)d_in[0];
  const float* gain1  = (const float*)d_in[1];
  const float* w_qkv  = (const float*)d_in[2];
  const float* mem_kv = (const float*)d_in[3];
  const float* w_out  = (const float*)d_in[4];
  const float* b_out  = (const float*)d_in[5];
  const float* gain2  = (const float*)d_in[6];
  float* out = (float*)d_out;

  char* ws = (char*)d_ws;
  // shared (weights) region
  u16* wqkvb = (u16*)ws;                         // 786,432 B
  u16* woutb = (u16*)(ws + 786432);              // 262,144 B
  size_t shared_b = 1048576;

  // per-batch chunk buffers
  const size_t xbT_b   = (size_t)N_ * C_ * 2;          //  2 MiB
  const size_t qkv_b   = (size_t)QKVC * N_ * 2;        // 12 MiB
  const size_t attnT_b = (size_t)HID * N_ * 2;         //  4 MiB
  const size_t ctxp_b  = (size_t)NH * 8 * 4160 * 4;    // ~1.02 MiB
  const size_t ctxf_b  = (size_t)NH * 4096 * 4;        // 128 KiB
  const size_t per_b   = xbT_b + qkv_b + attnT_b + ctxp_b + ctxf_b;

  int G = 16;
  while (G > 1 && shared_b + (size_t)G * per_b > ws_size) G >>= 1;

  char* base = ws + shared_b;
  u16*   xbT   = (u16*)base;
  u16*   qkv   = (u16*)(base + (size_t)G * xbT_b);
  u16*   attnT = (u16*)(base + (size_t)G * (xbT_b + qkv_b));
  float* ctxp  = (float*)(base + (size_t)G * (xbT_b + qkv_b + attnT_b));
  float* ctxf  = (float*)(base + (size_t)G * (xbT_b + qkv_b + attnT_b + ctxp_b));

  k_cvtw<<<256, 256, 0, stream>>>(w_qkv, w_out, wqkvb, woutb);

  for (int b0 = 0; b0 < B_; b0 += G) {
    const float* xc = x + (size_t)b0 * C_ * N_;
    float*       oc = out + (size_t)b0 * C_ * N_;
    k_rms1 <<<dim3(N_ / 256, G),      256, 0, stream>>>(xc, gain1, xbT);
    k_qkv  <<<dim3(QKVC / 128, N_ / 128, G), 256, 0, stream>>>(wqkvb, xbT, qkv);
    k_ctx2 <<<dim3(8, NH, G),         256, 0, stream>>>(qkv, ctxp);
    k_cfin <<<dim3(NH, G),            256, 0, stream>>>(ctxp, mem_kv, ctxf);
    k_pv   <<<dim3(N_ / 256, NH, G),  256, 0, stream>>>(qkv, ctxf, attnT);
    k_out  <<<dim3(N_ / 64, G),       256, 0, stream>>>(woutb, attnT, b_out, gain2, oc);
  }
}

// Round 4
// 324.853 us; speedup vs baseline: 2.3006x; 1.2203x over previous
//
#include <hip/hip_runtime.h>

typedef __attribute__((ext_vector_type(8))) short bf16x8;
typedef __attribute__((ext_vector_type(4))) float f32x4;
typedef unsigned short u16;

constexpr int B_   = 16;
constexpr int C_   = 256;
constexpr int NH   = 8;
constexpr int DH   = 64;
constexpr int NMEM = 4;
constexpr int HID  = 512;    // NH*DH
constexpr int QKVC = 1536;   // 3*HID
constexpr int N_   = 4096;   // 64*64

__device__ __forceinline__ u16 f2b(float f) {   // RNE f32->bf16
  union { float f; unsigned u; } v{f};
  unsigned r = v.u + 0x7fff + ((v.u >> 16) & 1);
  return (u16)(r >> 16);
}
__device__ __forceinline__ float b2f(u16 h) {
  union { unsigned u; float f; } v; v.u = ((unsigned)h) << 16; return v.f;
}

// ---------------- weights -> bf16 (once per call) ----------------
__global__ void k_cvtw(const float* __restrict__ wq, const float* __restrict__ wo,
                       u16* __restrict__ wqb, u16* __restrict__ wob) {
  int i = blockIdx.x * 256 + threadIdx.x;
  for (int idx = i; idx < QKVC * C_; idx += gridDim.x * 256) wqb[idx] = f2b(wq[idx]);
  for (int idx = i; idx < C_ * HID; idx += gridDim.x * 256) wob[idx] = f2b(wo[idx]);
}

// ---------------- rmsnorm1 + transpose to bf16 [g][n][c] ----------------
__global__ __launch_bounds__(256) void k_rms1(const float* __restrict__ x,
                                              const float* __restrict__ g1,
                                              u16* __restrict__ xbT) {
  int g = blockIdx.y;
  int n = blockIdx.x * 256 + threadIdx.x;
  const float* xp = x + (size_t)g * C_ * N_ + n;
  float ss = 0.f;
  #pragma unroll 8
  for (int c = 0; c < C_; ++c) { float v = xp[(size_t)c * N_]; ss += v * v; }
  float inv = 16.0f / fmaxf(sqrtf(ss), 1e-12f);
  u16* op = xbT + ((size_t)g * N_ + n) * C_;
  for (int c0 = 0; c0 < C_; c0 += 8) {
    union { bf16x8 v; u16 u[8]; } pk;
    #pragma unroll
    for (int j = 0; j < 8; ++j) pk.u[j] = f2b(xp[(size_t)(c0 + j) * N_] * inv * g1[c0 + j]);
    *(bf16x8*)(op + c0) = pk.v;
  }
}

// ---------------- QKV GEMM: qkv[g][o][n] = sum_c W[o][c]*Xn[c][n], bf16 MFMA ----------------
__global__ __launch_bounds__(256) void k_qkv(const u16* __restrict__ Wb,
                                             const u16* __restrict__ XT,
                                             u16* __restrict__ qkv) {
  constexpr int BM = 128, BN = 128, BK = 32;
  __shared__ __align__(16) u16 As[BM * BK];
  __shared__ __align__(16) u16 Bs[BN * BK];
  int g  = blockIdx.z;
  int o0 = blockIdx.x * BM;
  int n0 = blockIdx.y * BN;
  int t = threadIdx.x, wave = t >> 6, lane = t & 63;
  int wm = wave >> 1, wn = wave & 1;     // 2x2 wave grid, 64x64 per wave
  int kg = lane >> 4, lr = lane & 15;

  const u16* Ag = Wb + (size_t)o0 * C_;
  const u16* Bg = XT + ((size_t)g * N_ + n0) * C_;

  f32x4 acc[4][4];
  #pragma unroll
  for (int i = 0; i < 4; ++i)
    #pragma unroll
    for (int j = 0; j < 4; ++j) acc[i][j] = (f32x4)0.f;

  for (int k0 = 0; k0 < C_; k0 += BK) {
    #pragma unroll
    for (int i = 0; i < 2; ++i) {
      int id = t + 256 * i;
      int r = id >> 2, ch = id & 3;     // 128 rows x 4 16B-chunks
      *(bf16x8*)(As + r * 32 + ((ch ^ (r & 3)) * 8)) = *(const bf16x8*)(Ag + (size_t)r * C_ + k0 + ch * 8);
      *(bf16x8*)(Bs + r * 32 + ((ch ^ (r & 3)) * 8)) = *(const bf16x8*)(Bg + (size_t)r * C_ + k0 + ch * 8);
    }
    __syncthreads();
    bf16x8 a[4], bv[4];
    #pragma unroll
    for (int mf = 0; mf < 4; ++mf) {
      int r = wm * 64 + mf * 16 + lr;
      a[mf] = *(const bf16x8*)(As + r * 32 + ((kg ^ (r & 3)) * 8));
    }
    #pragma unroll
    for (int nf = 0; nf < 4; ++nf) {
      int r = wn * 64 + nf * 16 + lr;
      bv[nf] = *(const bf16x8*)(Bs + r * 32 + ((kg ^ (r & 3)) * 8));
    }
    #pragma unroll
    for (int mf = 0; mf < 4; ++mf)
      #pragma unroll
      for (int nf = 0; nf < 4; ++nf)
        acc[mf][nf] = __builtin_amdgcn_mfma_f32_16x16x32_bf16(a[mf], bv[nf], acc[mf][nf], 0, 0, 0);
    __syncthreads();
  }
  u16* Og = qkv + (size_t)g * QKVC * N_;
  #pragma unroll
  for (int mf = 0; mf < 4; ++mf)
    #pragma unroll
    for (int nf = 0; nf < 4; ++nf)
      #pragma unroll
      for (int j = 0; j < 4; ++j) {
        int row = o0 + wm * 64 + mf * 16 + kg * 4 + j;
        int col = n0 + wn * 64 + nf * 16 + lr;
        Og[(size_t)row * N_ + col] = f2b(acc[mf][nf][j]);
      }
}

// ---------------- context partials via MFMA: P=exp(K), C_p[d][e] = sum_n P[d][n] V[e][n] ----------------
__global__ __launch_bounds__(256) void k_ctx2(const u16* __restrict__ qkv,
                                              float* __restrict__ ctxp) {
  constexpr int TK = 128;                       // n per staging tile
  __shared__ __align__(16) u16 Pl[64 * TK];     // 16KB, swizzled
  __shared__ __align__(16) u16 Vl[64 * TK];     // 16KB, swizzled
  int g = blockIdx.z, h = blockIdx.y, nc = blockIdx.x;
  int t = threadIdx.x, wave = t >> 6, lane = t & 63;
  int kg = lane >> 4, lr = lane & 15;
  const u16* Kg = qkv + ((size_t)g * QKVC + HID + h * DH) * N_;
  const u16* Vg = qkv + ((size_t)g * QKVC + 2 * HID + h * DH) * N_;

  f32x4 acc[4];
  #pragma unroll
  for (int nf = 0; nf < 4; ++nf) acc[nf] = (f32x4)0.f;
  float rsum[4] = {0.f, 0.f, 0.f, 0.f};

  for (int it = 0; it < 4; ++it) {
    int n0 = nc * 512 + it * TK;
    #pragma unroll
    for (int s = 0; s < 4; ++s) {
      int cid = t + 256 * s;
      int r = cid >> 4, cc = cid & 15;          // 64 rows x 16 chunks of 8
      union { bf16x8 v; u16 u[8]; } kv_, vv, pw;
      kv_.v = *(const bf16x8*)(Kg + (size_t)r * N_ + n0 + cc * 8);
      vv.v  = *(const bf16x8*)(Vg + (size_t)r * N_ + n0 + cc * 8);
      #pragma unroll
      for (int j = 0; j < 8; ++j) {
        float p = __expf(b2f(kv_.u[j]));
        rsum[s] += p;
        pw.u[j] = f2b(p);
      }
      *(bf16x8*)(Pl + r * TK + ((cc ^ (r & 15)) * 8)) = pw.v;
      *(bf16x8*)(Vl + r * TK + ((cc ^ (r & 15)) * 8)) = vv.v;
    }
    __syncthreads();
    #pragma unroll
    for (int k = 0; k < 4; ++k) {
      int c = k * 4 + kg;
      bf16x8 af = *(const bf16x8*)(Pl + (wave * 16 + lr) * TK + ((c ^ lr) * 8));
      #pragma unroll
      for (int nf = 0; nf < 4; ++nf) {
        bf16x8 bfv = *(const bf16x8*)(Vl + (nf * 16 + lr) * TK + ((c ^ lr) * 8));
        acc[nf] = __builtin_amdgcn_mfma_f32_16x16x32_bf16(af, bfv, acc[nf], 0, 0, 0);
      }
    }
    __syncthreads();
  }
  float* cgp = ctxp + ((size_t)(g * NH + h) * 8 + nc) * 4160;
  #pragma unroll
  for (int nf = 0; nf < 4; ++nf)
    #pragma unroll
    for (int j = 0; j < 4; ++j) {
      int d = wave * 16 + kg * 4 + j;
      int e = nf * 16 + lr;
      cgp[d * 64 + e] = acc[nf][j];
    }
  #pragma unroll
  for (int s = 0; s < 4; ++s) {
    #pragma unroll
    for (int m = 1; m < 16; m <<= 1) rsum[s] += __shfl_xor(rsum[s], m);
  }
  if (lr == 0) {
    #pragma unroll
    for (int s = 0; s < 4; ++s) cgp[4096 + (wave * 4 + kg + 16 * s)] = rsum[s];
  }
}

// ---------------- finalize context: sum partials + mem terms, /s_d, -> bf16 transposed [e][d] ----------------
__global__ __launch_bounds__(256) void k_cfin(const float* __restrict__ ctxp,
                                              const float* __restrict__ memkv,
                                              u16* __restrict__ ctxTb) {
  int g = blockIdx.y, h = blockIdx.x;
  int t = threadIdx.x;
  __shared__ float emk[DH * NMEM];
  __shared__ float sd[DH];
  const float* mk = memkv + (size_t)h * DH * NMEM;
  const float* mv = memkv + (size_t)(NH + h) * DH * NMEM;
  const float* cp = ctxp + (size_t)(g * NH + h) * 8 * 4160;
  emk[t] = __expf(mk[t]);                      // t = d*4+j
  __syncthreads();
  if (t < DH) {
    float s = 0.f;
    #pragma unroll
    for (int p = 0; p < 8; ++p) s += cp[p * 4160 + 4096 + t];
    #pragma unroll
    for (int j = 0; j < NMEM; ++j) s += emk[t * 4 + j];
    sd[t] = s;
  }
  __syncthreads();
  u16* ct = ctxTb + (size_t)(g * NH + h) * 4096;
  #pragma unroll
  for (int i = 0; i < 16; ++i) {
    int idx = t + 256 * i;
    int d = idx >> 6, e = idx & 63;
    float v = 0.f;
    #pragma unroll
    for (int p = 0; p < 8; ++p) v += cp[p * 4160 + idx];
    #pragma unroll
    for (int j = 0; j < NMEM; ++j) v += emk[d * 4 + j] * mv[e * 4 + j];
    ct[e * 64 + d] = f2b(v / sd[d]);           // transposed, bf16
  }
}

// ---------------- q-softmax + PV via MFMA -> attnT[g][n][hid] bf16 ----------------
// out[n][e] = sum_d qsm[n][d] * ctxT[e][d];  m=n rows, B=ctxT, K=64
__global__ __launch_bounds__(256) void k_pv(const u16* __restrict__ qkv,
                                            const u16* __restrict__ ctxTb,
                                            u16* __restrict__ attnT) {
  int g = blockIdx.z, h = blockIdx.y;
  int t = threadIdx.x, wave = t >> 6, lane = t & 63;
  int kg = lane >> 4, lr = lane & 15;
  int n0 = blockIdx.x * 256;
  __shared__ __align__(16) u16 qs[256 * 64];   // [n][d] swizzled, 32KB
  __shared__ __align__(16) u16 cl[64 * 64];    // [e][d] swizzled, 8KB

  // stage ctxT (8KB)
  {
    const u16* cg = ctxTb + (size_t)(g * NH + h) * 4096;
    #pragma unroll
    for (int i = 0; i < 2; ++i) {
      int id = t + 256 * i;          // 0..511
      int r = id >> 3, c = id & 7;
      *(bf16x8*)(cl + r * 64 + ((c ^ (r & 7)) * 8)) = *(const bf16x8*)(cg + r * 64 + c * 8);
    }
  }
  // per-thread q column softmax (coalesced 128B/wave per d)
  const u16* Qg = qkv + ((size_t)g * QKVC + (size_t)h * DH) * N_ + n0 + t;
  float q[64]; float s = 0.f;
  #pragma unroll
  for (int d = 0; d < DH; ++d) { q[d] = __expf(b2f(Qg[(size_t)d * N_])); s += q[d]; }
  float inv = 0.125f / s;
  #pragma unroll
  for (int c = 0; c < 8; ++c) {
    union { bf16x8 v; u16 u[8]; } pk;
    #pragma unroll
    for (int j = 0; j < 8; ++j) pk.u[j] = f2b(q[c * 8 + j] * inv);
    *(bf16x8*)(qs + t * 64 + ((c ^ (t & 7)) * 8)) = pk.v;
  }
  __syncthreads();

  f32x4 acc[4][4];
  #pragma unroll
  for (int i = 0; i < 4; ++i)
    #pragma unroll
    for (int j = 0; j < 4; ++j) acc[i][j] = (f32x4)0.f;

  #pragma unroll
  for (int ks = 0; ks < 2; ++ks) {
    bf16x8 a[4], bv[4];
    #pragma unroll
    for (int mf = 0; mf < 4; ++mf) {
      int r = wave * 64 + mf * 16 + lr;
      a[mf] = *(const bf16x8*)(qs + r * 64 + (((ks * 4 + kg) ^ (r & 7)) * 8));
    }
    #pragma unroll
    for (int nf = 0; nf < 4; ++nf) {
      int r = nf * 16 + lr;
      bv[nf] = *(const bf16x8*)(cl + r * 64 + (((ks * 4 + kg) ^ (r & 7)) * 8));
    }
    #pragma unroll
    for (int mf = 0; mf < 4; ++mf)
      #pragma unroll
      for (int nf = 0; nf < 4; ++nf)
        acc[mf][nf] = __builtin_amdgcn_mfma_f32_16x16x32_bf16(a[mf], bv[nf], acc[mf][nf], 0, 0, 0);
  }

  u16* op = attnT + ((size_t)g * N_ + n0) * HID + h * DH;
  #pragma unroll
  for (int mf = 0; mf < 4; ++mf)
    #pragma unroll
    for (int nf = 0; nf < 4; ++nf)
      #pragma unroll
      for (int j = 0; j < 4; ++j) {
        int n = wave * 64 + mf * 16 + kg * 4 + j;
        int e = nf * 16 + lr;                    // 16 lanes -> 32B contiguous
        op[(size_t)n * HID + e] = f2b(acc[mf][nf][j]);
      }
}

// ---------------- out-proj GEMM + bias + fused rmsnorm2 ----------------
__global__ __launch_bounds__(256) void k_out(const u16* __restrict__ Wb,
                                             const u16* __restrict__ AT,
                                             const float* __restrict__ bias,
                                             const float* __restrict__ g2,
                                             float* __restrict__ out) {
  constexpr int BN = 64, BK = 32;
  __shared__ __align__(16) u16 As[256 * BK];   // 16KB
  __shared__ __align__(16) u16 Bs[BN * BK];    // 4KB
  __shared__ float part[4][BN];
  int g  = blockIdx.y;
  int n0 = blockIdx.x * BN;
  int t = threadIdx.x, wave = t >> 6, lane = t & 63;
  int kg = lane >> 4, lr = lane & 15;

  const u16* Bg = AT + ((size_t)g * N_ + n0) * HID;

  f32x4 acc[4][4];
  #pragma unroll
  for (int i = 0; i < 4; ++i)
    #pragma unroll
    for (int j = 0; j < 4; ++j) acc[i][j] = (f32x4)0.f;

  for (int k0 = 0; k0 < HID; k0 += BK) {
    #pragma unroll
    for (int i = 0; i < 4; ++i) {
      int id = t + 256 * i;
      int r = id >> 2, ch = id & 3;      // 256 rows x 4 chunks
      *(bf16x8*)(As + r * 32 + ((ch ^ (r & 3)) * 8)) = *(const bf16x8*)(Wb + (size_t)r * HID + k0 + ch * 8);
    }
    {
      int r = t >> 2, ch = t & 3;        // 64 rows x 4 chunks
      *(bf16x8*)(Bs + r * 32 + ((ch ^ (r & 3)) * 8)) = *(const bf16x8*)(Bg + (size_t)r * HID + k0 + ch * 8);
    }
    __syncthreads();
    bf16x8 a[4], bv[4];
    #pragma unroll
    for (int mf = 0; mf < 4; ++mf) {
      int r = wave * 64 + mf * 16 + lr;
      a[mf] = *(const bf16x8*)(As + r * 32 + ((kg ^ (r & 3)) * 8));
    }
    #pragma unroll
    for (int nf = 0; nf < 4; ++nf) {
      int r = nf * 16 + lr;
      bv[nf] = *(const bf16x8*)(Bs + r * 32 + ((kg ^ (r & 3)) * 8));
    }
    #pragma unroll
    for (int mf = 0; mf < 4; ++mf)
      #pragma unroll
      for (int nf = 0; nf < 4; ++nf)
        acc[mf][nf] = __builtin_amdgcn_mfma_f32_16x16x32_bf16(a[mf], bv[nf], acc[mf][nf], 0, 0, 0);
    __syncthreads();
  }
  float colsq[4] = {0.f, 0.f, 0.f, 0.f};
  #pragma unroll
  for (int mf = 0; mf < 4; ++mf)
    #pragma unroll
    for (int j = 0; j < 4; ++j) {
      int row = wave * 64 + mf * 16 + kg * 4 + j;
      float bs = bias[row];
      #pragma unroll
      for (int nf = 0; nf < 4; ++nf) {
        float v = acc[mf][nf][j] + bs;
        acc[mf][nf][j] = v;
        colsq[nf] += v * v;
      }
    }
  #pragma unroll
  for (int nf = 0; nf < 4; ++nf) {
    colsq[nf] += __shfl_xor(colsq[nf], 16);
    colsq[nf] += __shfl_xor(colsq[nf], 32);
  }
  if (kg == 0) {
    #pragma unroll
    for (int nf = 0; nf < 4; ++nf) part[wave][nf * 16 + lr] = colsq[nf];
  }
  __syncthreads();
  float* og = out + (size_t)g * C_ * N_ + n0;
  #pragma unroll
  for (int nf = 0; nf < 4; ++nf) {
    int col = nf * 16 + lr;
    float tot = part[0][col] + part[1][col] + part[2][col] + part[3][col];
    float invn = 16.0f / fmaxf(sqrtf(tot), 1e-12f);
    #pragma unroll
    for (int mf = 0; mf < 4; ++mf)
      #pragma unroll
      for (int j = 0; j < 4; ++j) {
        int row = wave * 64 + mf * 16 + kg * 4 + j;
        og[(size_t)row * N_ + col] = acc[mf][nf][j] * invn * g2[row];
      }
  }
}

extern "C" void kernel_launch(void* const* d_in, const int* in_sizes, int n_in,
                              void* d_out, int out_size, void* d_ws, size_t ws_size,
                              hipStream_t stream) {
  (void)in_sizes; (void)n_in; (void)out_size;
  const float* x      = (const float*)d_in[0];
  const float* gain1  = (const float*)d_in[1];
  const float* w_qkv  = (const float*)d_in[2];
  const float* mem_kv = (const float*)d_in[3];
  const float* w_out  = (const float*)d_in[4];
  const float* b_out  = (const float*)d_in[5];
  const float* gain2  = (const float*)d_in[6];
  float* out = (float*)d_out;

  char* ws = (char*)d_ws;
  u16* wqkvb = (u16*)ws;                         // 786,432 B
  u16* woutb = (u16*)(ws + 786432);              // 262,144 B
  size_t shared_b = 1048576;

  const size_t xbT_b   = (size_t)N_ * C_ * 2;          //  2 MiB
  const size_t qkv_b   = (size_t)QKVC * N_ * 2;        // 12 MiB
  const size_t attnT_b = (size_t)HID * N_ * 2;         //  4 MiB
  const size_t ctxp_b  = (size_t)NH * 8 * 4160 * 4;    // ~1.02 MiB
  const size_t ctxT_b  = (size_t)NH * 4096 * 2;        // 64 KiB
  const size_t per_b   = xbT_b + qkv_b + attnT_b + ctxp_b + ctxT_b;

  int G = 16;
  while (G > 1 && shared_b + (size_t)G * per_b > ws_size) G >>= 1;

  char* base = ws + shared_b;
  u16*   xbT   = (u16*)base;
  u16*   qkv   = (u16*)(base + (size_t)G * xbT_b);
  u16*   attnT = (u16*)(base + (size_t)G * (xbT_b + qkv_b));
  float* ctxp  = (float*)(base + (size_t)G * (xbT_b + qkv_b + attnT_b));
  u16*   ctxTb = (u16*)(base + (size_t)G * (xbT_b + qkv_b + attnT_b + ctxp_b));

  k_cvtw<<<256, 256, 0, stream>>>(w_qkv, w_out, wqkvb, woutb);

  for (int b0 = 0; b0 < B_; b0 += G) {
    const float* xc = x + (size_t)b0 * C_ * N_;
    float*       oc = out + (size_t)b0 * C_ * N_;
    k_rms1 <<<dim3(N_ / 256, G),      256, 0, stream>>>(xc, gain1, xbT);
    k_qkv  <<<dim3(QKVC / 128, N_ / 128, G), 256, 0, stream>>>(wqkvb, xbT, qkv);
    k_ctx2 <<<dim3(8, NH, G),         256, 0, stream>>>(qkv, ctxp);
    k_cfin <<<dim3(NH, G),            256, 0, stream>>>(ctxp, mem_kv, ctxTb);
    k_pv   <<<dim3(N_ / 256, NH, G),  256, 0, stream>>>(qkv, ctxTb, attnT);
    k_out  <<<dim3(N_ / 64, G),       256, 0, stream>>>(woutb, attnT, b_out, gain2, oc);
  }
}

// Round 5
// 305.160 us; speedup vs baseline: 2.4491x; 1.0645x over previous
//
#include <hip/hip_runtime.h>

typedef __attribute__((ext_vector_type(8))) short bf16x8;
typedef __attribute__((ext_vector_type(4))) float f32x4;
typedef unsigned short u16;

constexpr int B_   = 16;
constexpr int C_   = 256;
constexpr int NH   = 8;
constexpr int DH   = 64;
constexpr int NMEM = 4;
constexpr int HID  = 512;    // NH*DH
constexpr int QKVC = 1536;   // 3*HID
constexpr int N_   = 4096;   // 64*64

__device__ __forceinline__ u16 f2b(float f) {   // RNE f32->bf16
  union { float f; unsigned u; } v{f};
  unsigned r = v.u + 0x7fff + ((v.u >> 16) & 1);
  return (u16)(r >> 16);
}
__device__ __forceinline__ float b2f(u16 h) {
  union { unsigned u; float f; } v; v.u = ((unsigned)h) << 16; return v.f;
}

// async global->LDS, 16B per lane; lds dest = wave-uniform base + lane*16B
__device__ __forceinline__ void gld_lds16(const u16* g, u16* l) {
  __builtin_amdgcn_global_load_lds(
      (const __attribute__((address_space(1))) unsigned*)g,
      (__attribute__((address_space(3))) unsigned*)l, 16, 0, 0);
}

// ---------------- weights -> bf16 (once per call) ----------------
__global__ void k_cvtw(const float* __restrict__ wq, const float* __restrict__ wo,
                       u16* __restrict__ wqb, u16* __restrict__ wob) {
  int i = blockIdx.x * 256 + threadIdx.x;
  for (int idx = i; idx < QKVC * C_; idx += gridDim.x * 256) wqb[idx] = f2b(wq[idx]);
  for (int idx = i; idx < C_ * HID; idx += gridDim.x * 256) wob[idx] = f2b(wo[idx]);
}

// ---------------- rmsnorm1 + transpose to bf16 [g][n][c] ----------------
__global__ __launch_bounds__(256) void k_rms1(const float* __restrict__ x,
                                              const float* __restrict__ g1,
                                              u16* __restrict__ xbT) {
  int g = blockIdx.y;
  int n = blockIdx.x * 256 + threadIdx.x;
  const float* xp = x + (size_t)g * C_ * N_ + n;
  float ss = 0.f;
  #pragma unroll 8
  for (int c = 0; c < C_; ++c) { float v = xp[(size_t)c * N_]; ss += v * v; }
  float inv = 16.0f / fmaxf(sqrtf(ss), 1e-12f);
  u16* op = xbT + ((size_t)g * N_ + n) * C_;
  for (int c0 = 0; c0 < C_; c0 += 8) {
    union { bf16x8 v; u16 u[8]; } pk;
    #pragma unroll
    for (int j = 0; j < 8; ++j) pk.u[j] = f2b(xp[(size_t)(c0 + j) * N_] * inv * g1[c0 + j]);
    *(bf16x8*)(op + c0) = pk.v;
  }
}

// ---------------- QKV GEMM: qkv[g][o][n] = sum_c W[o][c]*Xn[c][n], bf16 MFMA ----------------
// staging via global_load_lds: linear LDS dest, inverse-swizzled global source (rule 21)
__global__ __launch_bounds__(256) void k_qkv(const u16* __restrict__ Wb,
                                             const u16* __restrict__ XT,
                                             u16* __restrict__ qkv) {
  constexpr int BM = 128, BN = 128, BK = 32;
  __shared__ __align__(16) u16 As[BM * BK];
  __shared__ __align__(16) u16 Bs[BN * BK];
  int g  = blockIdx.z;
  int o0 = blockIdx.x * BM;
  int n0 = blockIdx.y * BN;
  int t = threadIdx.x, wave = t >> 6, lane = t & 63;
  int wm = wave >> 1, wn = wave & 1;     // 2x2 wave grid, 64x64 per wave
  int kg = lane >> 4, lr = lane & 15;

  const u16* Ag = Wb + (size_t)o0 * C_;
  const u16* Bg = XT + ((size_t)g * N_ + n0) * C_;

  // staging address components: lane covers row rloc=lane>>2, chunk (lane&3)^(rloc&3)
  int rloc = lane >> 2;
  int cswz = (lane & 3) ^ (rloc & 3);

  f32x4 acc[4][4];
  #pragma unroll
  for (int i = 0; i < 4; ++i)
    #pragma unroll
    for (int j = 0; j < 4; ++j) acc[i][j] = (f32x4)0.f;

  for (int k0 = 0; k0 < C_; k0 += BK) {
    #pragma unroll
    for (int q = 0; q < 2; ++q) {
      int r = wave * 32 + q * 16 + rloc;          // r&3 == rloc&3
      gld_lds16(Ag + (size_t)r * C_ + k0 + cswz * 8, As + (wave * 32 + q * 16) * 32);
      gld_lds16(Bg + (size_t)r * C_ + k0 + cswz * 8, Bs + (wave * 32 + q * 16) * 32);
    }
    __syncthreads();
    bf16x8 a[4], bv[4];
    #pragma unroll
    for (int mf = 0; mf < 4; ++mf) {
      int r = wm * 64 + mf * 16 + lr;
      a[mf] = *(const bf16x8*)(As + r * 32 + ((kg ^ (r & 3)) * 8));
    }
    #pragma unroll
    for (int nf = 0; nf < 4; ++nf) {
      int r = wn * 64 + nf * 16 + lr;
      bv[nf] = *(const bf16x8*)(Bs + r * 32 + ((kg ^ (r & 3)) * 8));
    }
    #pragma unroll
    for (int mf = 0; mf < 4; ++mf)
      #pragma unroll
      for (int nf = 0; nf < 4; ++nf)
        acc[mf][nf] = __builtin_amdgcn_mfma_f32_16x16x32_bf16(a[mf], bv[nf], acc[mf][nf], 0, 0, 0);
    __syncthreads();
  }
  u16* Og = qkv + (size_t)g * QKVC * N_;
  #pragma unroll
  for (int mf = 0; mf < 4; ++mf)
    #pragma unroll
    for (int nf = 0; nf < 4; ++nf)
      #pragma unroll
      for (int j = 0; j < 4; ++j) {
        int row = o0 + wm * 64 + mf * 16 + kg * 4 + j;
        int col = n0 + wn * 64 + nf * 16 + lr;
        Og[(size_t)row * N_ + col] = f2b(acc[mf][nf][j]);
      }
}

// ---------------- context partials via MFMA: P=exp(K), C_p[d][e] = sum_n P[d][n] V[e][n] ----------------
__global__ __launch_bounds__(256) void k_ctx2(const u16* __restrict__ qkv,
                                              float* __restrict__ ctxp) {
  constexpr int TK = 128;                       // n per staging tile
  __shared__ __align__(16) u16 Pl[64 * TK];     // 16KB, swizzled
  __shared__ __align__(16) u16 Vl[64 * TK];     // 16KB, swizzled
  int g = blockIdx.z, h = blockIdx.y, nc = blockIdx.x;
  int t = threadIdx.x, wave = t >> 6, lane = t & 63;
  int kg = lane >> 4, lr = lane & 15;
  const u16* Kg = qkv + ((size_t)g * QKVC + HID + h * DH) * N_;
  const u16* Vg = qkv + ((size_t)g * QKVC + 2 * HID + h * DH) * N_;

  f32x4 acc[4];
  #pragma unroll
  for (int nf = 0; nf < 4; ++nf) acc[nf] = (f32x4)0.f;
  float rsum[4] = {0.f, 0.f, 0.f, 0.f};

  for (int it = 0; it < 4; ++it) {
    int n0 = nc * 512 + it * TK;
    #pragma unroll
    for (int s = 0; s < 4; ++s) {
      int cid = t + 256 * s;
      int r = cid >> 4, cc = cid & 15;          // 64 rows x 16 chunks of 8
      union { bf16x8 v; u16 u[8]; } kv_, vv, pw;
      kv_.v = *(const bf16x8*)(Kg + (size_t)r * N_ + n0 + cc * 8);
      vv.v  = *(const bf16x8*)(Vg + (size_t)r * N_ + n0 + cc * 8);
      #pragma unroll
      for (int j = 0; j < 8; ++j) {
        float p = __expf(b2f(kv_.u[j]));
        rsum[s] += p;
        pw.u[j] = f2b(p);
      }
      *(bf16x8*)(Pl + r * TK + ((cc ^ (r & 15)) * 8)) = pw.v;
      *(bf16x8*)(Vl + r * TK + ((cc ^ (r & 15)) * 8)) = vv.v;
    }
    __syncthreads();
    #pragma unroll
    for (int k = 0; k < 4; ++k) {
      int c = k * 4 + kg;
      bf16x8 af = *(const bf16x8*)(Pl + (wave * 16 + lr) * TK + ((c ^ lr) * 8));
      #pragma unroll
      for (int nf = 0; nf < 4; ++nf) {
        bf16x8 bfv = *(const bf16x8*)(Vl + (nf * 16 + lr) * TK + ((c ^ lr) * 8));
        acc[nf] = __builtin_amdgcn_mfma_f32_16x16x32_bf16(af, bfv, acc[nf], 0, 0, 0);
      }
    }
    __syncthreads();
  }
  float* cgp = ctxp + ((size_t)(g * NH + h) * 8 + nc) * 4160;
  #pragma unroll
  for (int nf = 0; nf < 4; ++nf)
    #pragma unroll
    for (int j = 0; j < 4; ++j) {
      int d = wave * 16 + kg * 4 + j;
      int e = nf * 16 + lr;
      cgp[d * 64 + e] = acc[nf][j];
    }
  #pragma unroll
  for (int s = 0; s < 4; ++s) {
    #pragma unroll
    for (int m = 1; m < 16; m <<= 1) rsum[s] += __shfl_xor(rsum[s], m);
  }
  if (lr == 0) {
    #pragma unroll
    for (int s = 0; s < 4; ++s) cgp[4096 + (wave * 4 + kg + 16 * s)] = rsum[s];
  }
}

// ---------------- finalize context: sum partials + mem terms, /s_d, -> bf16 transposed [e][d] ----------------
__global__ __launch_bounds__(256) void k_cfin(const float* __restrict__ ctxp,
                                              const float* __restrict__ memkv,
                                              u16* __restrict__ ctxTb) {
  int g = blockIdx.y, h = blockIdx.x;
  int t = threadIdx.x;
  __shared__ float emk[DH * NMEM];
  __shared__ float sd[DH];
  const float* mk = memkv + (size_t)h * DH * NMEM;
  const float* mv = memkv + (size_t)(NH + h) * DH * NMEM;
  const float* cp = ctxp + (size_t)(g * NH + h) * 8 * 4160;
  emk[t] = __expf(mk[t]);                      // t = d*4+j
  __syncthreads();
  if (t < DH) {
    float s = 0.f;
    #pragma unroll
    for (int p = 0; p < 8; ++p) s += cp[p * 4160 + 4096 + t];
    #pragma unroll
    for (int j = 0; j < NMEM; ++j) s += emk[t * 4 + j];
    sd[t] = s;
  }
  __syncthreads();
  u16* ct = ctxTb + (size_t)(g * NH + h) * 4096;
  #pragma unroll
  for (int i = 0; i < 16; ++i) {
    int idx = t + 256 * i;
    int d = idx >> 6, e = idx & 63;
    float v = 0.f;
    #pragma unroll
    for (int p = 0; p < 8; ++p) v += cp[p * 4160 + idx];
    #pragma unroll
    for (int j = 0; j < NMEM; ++j) v += emk[d * 4 + j] * mv[e * 4 + j];
    ct[e * 64 + d] = f2b(v / sd[d]);           // transposed, bf16
  }
}

// ---------------- q-softmax + PV via MFMA -> attnT[g][n][hid] bf16 ----------------
__global__ __launch_bounds__(256) void k_pv(const u16* __restrict__ qkv,
                                            const u16* __restrict__ ctxTb,
                                            u16* __restrict__ attnT) {
  int g = blockIdx.z, h = blockIdx.y;
  int t = threadIdx.x, wave = t >> 6, lane = t & 63;
  int kg = lane >> 4, lr = lane & 15;
  int n0 = blockIdx.x * 256;
  __shared__ __align__(16) u16 qs[256 * 64];   // [n][d] swizzled, 32KB
  __shared__ __align__(16) u16 cl[64 * 64];    // [e][d] swizzled, 8KB

  {
    const u16* cg = ctxTb + (size_t)(g * NH + h) * 4096;
    #pragma unroll
    for (int i = 0; i < 2; ++i) {
      int id = t + 256 * i;          // 0..511
      int r = id >> 3, c = id & 7;
      *(bf16x8*)(cl + r * 64 + ((c ^ (r & 7)) * 8)) = *(const bf16x8*)(cg + r * 64 + c * 8);
    }
  }
  const u16* Qg = qkv + ((size_t)g * QKVC + (size_t)h * DH) * N_ + n0 + t;
  float q[64]; float s = 0.f;
  #pragma unroll
  for (int d = 0; d < DH; ++d) { q[d] = __expf(b2f(Qg[(size_t)d * N_])); s += q[d]; }
  float inv = 0.125f / s;
  #pragma unroll
  for (int c = 0; c < 8; ++c) {
    union { bf16x8 v; u16 u[8]; } pk;
    #pragma unroll
    for (int j = 0; j < 8; ++j) pk.u[j] = f2b(q[c * 8 + j] * inv);
    *(bf16x8*)(qs + t * 64 + ((c ^ (t & 7)) * 8)) = pk.v;
  }
  __syncthreads();

  f32x4 acc[4][4];
  #pragma unroll
  for (int i = 0; i < 4; ++i)
    #pragma unroll
    for (int j = 0; j < 4; ++j) acc[i][j] = (f32x4)0.f;

  #pragma unroll
  for (int ks = 0; ks < 2; ++ks) {
    bf16x8 a[4], bv[4];
    #pragma unroll
    for (int mf = 0; mf < 4; ++mf) {
      int r = wave * 64 + mf * 16 + lr;
      a[mf] = *(const bf16x8*)(qs + r * 64 + (((ks * 4 + kg) ^ (r & 7)) * 8));
    }
    #pragma unroll
    for (int nf = 0; nf < 4; ++nf) {
      int r = nf * 16 + lr;
      bv[nf] = *(const bf16x8*)(cl + r * 64 + (((ks * 4 + kg) ^ (r & 7)) * 8));
    }
    #pragma unroll
    for (int mf = 0; mf < 4; ++mf)
      #pragma unroll
      for (int nf = 0; nf < 4; ++nf)
        acc[mf][nf] = __builtin_amdgcn_mfma_f32_16x16x32_bf16(a[mf], bv[nf], acc[mf][nf], 0, 0, 0);
  }

  u16* op = attnT + ((size_t)g * N_ + n0) * HID + h * DH;
  #pragma unroll
  for (int mf = 0; mf < 4; ++mf)
    #pragma unroll
    for (int nf = 0; nf < 4; ++nf)
      #pragma unroll
      for (int j = 0; j < 4; ++j) {
        int n = wave * 64 + mf * 16 + kg * 4 + j;
        int e = nf * 16 + lr;
        op[(size_t)n * HID + e] = f2b(acc[mf][nf][j]);
      }
}

// ---------------- out-proj GEMM + bias + fused rmsnorm2 ----------------
__global__ __launch_bounds__(256) void k_out(const u16* __restrict__ Wb,
                                             const u16* __restrict__ AT,
                                             const float* __restrict__ bias,
                                             const float* __restrict__ g2,
                                             float* __restrict__ out) {
  constexpr int BN = 64, BK = 32;
  __shared__ __align__(16) u16 As[256 * BK];   // 16KB
  __shared__ __align__(16) u16 Bs[BN * BK];    // 4KB
  __shared__ float part[4][BN];
  int g  = blockIdx.y;
  int n0 = blockIdx.x * BN;
  int t = threadIdx.x, wave = t >> 6, lane = t & 63;
  int kg = lane >> 4, lr = lane & 15;

  const u16* Bg = AT + ((size_t)g * N_ + n0) * HID;

  int rloc = lane >> 2;
  int cswz = (lane & 3) ^ (rloc & 3);

  f32x4 acc[4][4];
  #pragma unroll
  for (int i = 0; i < 4; ++i)
    #pragma unroll
    for (int j = 0; j < 4; ++j) acc[i][j] = (f32x4)0.f;

  for (int k0 = 0; k0 < HID; k0 += BK) {
    #pragma unroll
    for (int q = 0; q < 4; ++q) {
      int r = wave * 64 + q * 16 + rloc;
      gld_lds16(Wb + (size_t)r * HID + k0 + cswz * 8, As + (wave * 64 + q * 16) * 32);
    }
    {
      int r = wave * 16 + rloc;
      gld_lds16(Bg + (size_t)r * HID + k0 + cswz * 8, Bs + (wave * 16) * 32);
    }
    __syncthreads();
    bf16x8 a[4], bv[4];
    #pragma unroll
    for (int mf = 0; mf < 4; ++mf) {
      int r = wave * 64 + mf * 16 + lr;
      a[mf] = *(const bf16x8*)(As + r * 32 + ((kg ^ (r & 3)) * 8));
    }
    #pragma unroll
    for (int nf = 0; nf < 4; ++nf) {
      int r = nf * 16 + lr;
      bv[nf] = *(const bf16x8*)(Bs + r * 32 + ((kg ^ (r & 3)) * 8));
    }
    #pragma unroll
    for (int mf = 0; mf < 4; ++mf)
      #pragma unroll
      for (int nf = 0; nf < 4; ++nf)
        acc[mf][nf] = __builtin_amdgcn_mfma_f32_16x16x32_bf16(a[mf], bv[nf], acc[mf][nf], 0, 0, 0);
    __syncthreads();
  }
  float colsq[4] = {0.f, 0.f, 0.f, 0.f};
  #pragma unroll
  for (int mf = 0; mf < 4; ++mf)
    #pragma unroll
    for (int j = 0; j < 4; ++j) {
      int row = wave * 64 + mf * 16 + kg * 4 + j;
      float bs = bias[row];
      #pragma unroll
      for (int nf = 0; nf < 4; ++nf) {
        float v = acc[mf][nf][j] + bs;
        acc[mf][nf][j] = v;
        colsq[nf] += v * v;
      }
    }
  #pragma unroll
  for (int nf = 0; nf < 4; ++nf) {
    colsq[nf] += __shfl_xor(colsq[nf], 16);
    colsq[nf] += __shfl_xor(colsq[nf], 32);
  }
  if (kg == 0) {
    #pragma unroll
    for (int nf = 0; nf < 4; ++nf) part[wave][nf * 16 + lr] = colsq[nf];
  }
  __syncthreads();
  float* og = out + (size_t)g * C_ * N_ + n0;
  #pragma unroll
  for (int nf = 0; nf < 4; ++nf) {
    int col = nf * 16 + lr;
    float tot = part[0][col] + part[1][col] + part[2][col] + part[3][col];
    float invn = 16.0f / fmaxf(sqrtf(tot), 1e-12f);
    #pragma unroll
    for (int mf = 0; mf < 4; ++mf)
      #pragma unroll
      for (int j = 0; j < 4; ++j) {
        int row = wave * 64 + mf * 16 + kg * 4 + j;
        og[(size_t)row * N_ + col] = acc[mf][nf][j] * invn * g2[row];
      }
  }
}

extern "C" void kernel_launch(void* const* d_in, const int* in_sizes, int n_in,
                              void* d_out, int out_size, void* d_ws, size_t ws_size,
                              hipStream_t stream) {
  (void)in_sizes; (void)n_in; (void)out_size;
  const float* x      = (const float*)d_in[0];
  const float* gain1  = (const float*)d_in[1];
  const float* w_qkv  = (const float*)d_in[2];
  const float* mem_kv = (const float*)d_in[3];
  const float* w_out  = (const float*)d_in[4];
  const float* b_out  = (const float*)d_in[5];
  const float* gain2  = (const float*)d_in[6];
  float* out = (float*)d_out;

  char* ws = (char*)d_ws;
  u16* wqkvb = (u16*)ws;                         // 786,432 B
  u16* woutb = (u16*)(ws + 786432);              // 262,144 B
  size_t shared_b = 1048576;

  const size_t xbT_b   = (size_t)N_ * C_ * 2;          //  2 MiB
  const size_t qkv_b   = (size_t)QKVC * N_ * 2;        // 12 MiB
  const size_t attnT_b = (size_t)HID * N_ * 2;         //  4 MiB
  const size_t ctxp_b  = (size_t)NH * 8 * 4160 * 4;    // ~1.02 MiB
  const size_t ctxT_b  = (size_t)NH * 4096 * 2;        // 64 KiB
  const size_t per_b   = xbT_b + qkv_b + attnT_b + ctxp_b + ctxT_b;

  int G = 16;
  while (G > 1 && shared_b + (size_t)G * per_b > ws_size) G >>= 1;

  char* base = ws + shared_b;
  u16*   xbT   = (u16*)base;
  u16*   qkv   = (u16*)(base + (size_t)G * xbT_b);
  u16*   attnT = (u16*)(base + (size_t)G * (xbT_b + qkv_b));
  float* ctxp  = (float*)(base + (size_t)G * (xbT_b + qkv_b + attnT_b));
  u16*   ctxTb = (u16*)(base + (size_t)G * (xbT_b + qkv_b + attnT_b + ctxp_b));

  k_cvtw<<<256, 256, 0, stream>>>(w_qkv, w_out, wqkvb, woutb);

  for (int b0 = 0; b0 < B_; b0 += G) {
    const float* xc = x + (size_t)b0 * C_ * N_;
    float*       oc = out + (size_t)b0 * C_ * N_;
    k_rms1 <<<dim3(N_ / 256, G),      256, 0, stream>>>(xc, gain1, xbT);
    k_qkv  <<<dim3(QKVC / 128, N_ / 128, G), 256, 0, stream>>>(wqkvb, xbT, qkv);
    k_ctx2 <<<dim3(8, NH, G),         256, 0, stream>>>(qkv, ctxp);
    k_cfin <<<dim3(NH, G),            256, 0, stream>>>(ctxp, mem_kv, ctxTb);
    k_pv   <<<dim3(N_ / 256, NH, G),  256, 0, stream>>>(qkv, ctxTb, attnT);
    k_out  <<<dim3(N_ / 64, G),       256, 0, stream>>>(woutb, attnT, b_out, gain2, oc);
  }
}

// Round 6
// 304.057 us; speedup vs baseline: 2.4580x; 1.0036x over previous
//
#include <hip/hip_runtime.h>

typedef __attribute__((ext_vector_type(8))) short bf16x8;
typedef __attribute__((ext_vector_type(4))) float f32x4;
typedef unsigned short u16;

constexpr int B_   = 16;
constexpr int C_   = 256;
constexpr int NH   = 8;
constexpr int DH   = 64;
constexpr int NMEM = 4;
constexpr int HID  = 512;    // NH*DH
constexpr int QKVC = 1536;   // 3*HID
constexpr int N_   = 4096;   // 64*64

__device__ __forceinline__ u16 f2b(float f) {   // RNE f32->bf16
  union { float f; unsigned u; } v{f};
  unsigned r = v.u + 0x7fff + ((v.u >> 16) & 1);
  return (u16)(r >> 16);
}
__device__ __forceinline__ float b2f(u16 h) {
  union { unsigned u; float f; } v; v.u = ((unsigned)h) << 16; return v.f;
}

// async global->LDS, 16B per lane; lds dest = wave-uniform base + lane*16B
__device__ __forceinline__ void gld_lds16(const u16* g, u16* l) {
  __builtin_amdgcn_global_load_lds(
      (const __attribute__((address_space(1))) unsigned*)g,
      (__attribute__((address_space(3))) unsigned*)l, 16, 0, 0);
}

// ---------------- weights -> bf16 (once per call) ----------------
__global__ void k_cvtw(const float* __restrict__ wq, const float* __restrict__ wo,
                       u16* __restrict__ wqb, u16* __restrict__ wob) {
  int i = blockIdx.x * 256 + threadIdx.x;
  for (int idx = i; idx < QKVC * C_; idx += gridDim.x * 256) wqb[idx] = f2b(wq[idx]);
  for (int idx = i; idx < C_ * HID; idx += gridDim.x * 256) wob[idx] = f2b(wo[idx]);
}

// ---------------- rmsnorm1 + transpose to bf16 [g][n][c] ----------------
__global__ __launch_bounds__(256) void k_rms1(const float* __restrict__ x,
                                              const float* __restrict__ g1,
                                              u16* __restrict__ xbT) {
  int g = blockIdx.y;
  int n = blockIdx.x * 256 + threadIdx.x;
  const float* xp = x + (size_t)g * C_ * N_ + n;
  float ss = 0.f;
  #pragma unroll 8
  for (int c = 0; c < C_; ++c) { float v = xp[(size_t)c * N_]; ss += v * v; }
  float inv = 16.0f / fmaxf(sqrtf(ss), 1e-12f);
  u16* op = xbT + ((size_t)g * N_ + n) * C_;
  for (int c0 = 0; c0 < C_; c0 += 8) {
    union { bf16x8 v; u16 u[8]; } pk;
    #pragma unroll
    for (int j = 0; j < 8; ++j) pk.u[j] = f2b(xp[(size_t)(c0 + j) * N_] * inv * g1[c0 + j]);
    *(bf16x8*)(op + c0) = pk.v;
  }
}

// ---------------- QKV GEMM: qkv[g][o][n] = sum_c W[o][c]*Xn[c][n], bf16 MFMA ----------------
// 1-D grid + XCD swizzle: logical L = ob + 12*nb + 384*g; XCD k owns contiguous L-chunk
__global__ __launch_bounds__(256) void k_qkv(const u16* __restrict__ Wb,
                                             const u16* __restrict__ XT,
                                             u16* __restrict__ qkv) {
  constexpr int BM = 128, BN = 128, BK = 32;
  __shared__ __align__(16) u16 As[BM * BK];
  __shared__ __align__(16) u16 Bs[BN * BK];
  int cpx = gridDim.x >> 3;                 // nwg/8 (nwg = 384*G, always %8==0)
  int bid = blockIdx.x;
  int L = (bid & 7) * cpx + (bid >> 3);
  int ob = L % 12, rest = L / 12;
  int nb = rest & 31, g = rest >> 5;
  int o0 = ob * BM;
  int n0 = nb * BN;
  int t = threadIdx.x, wave = t >> 6, lane = t & 63;
  int wm = wave >> 1, wn = wave & 1;     // 2x2 wave grid, 64x64 per wave
  int kg = lane >> 4, lr = lane & 15;

  const u16* Ag = Wb + (size_t)o0 * C_;
  const u16* Bg = XT + ((size_t)g * N_ + n0) * C_;

  int rloc = lane >> 2;
  int cswz = (lane & 3) ^ (rloc & 3);

  f32x4 acc[4][4];
  #pragma unroll
  for (int i = 0; i < 4; ++i)
    #pragma unroll
    for (int j = 0; j < 4; ++j) acc[i][j] = (f32x4)0.f;

  for (int k0 = 0; k0 < C_; k0 += BK) {
    #pragma unroll
    for (int q = 0; q < 2; ++q) {
      int r = wave * 32 + q * 16 + rloc;          // r&3 == rloc&3
      gld_lds16(Ag + (size_t)r * C_ + k0 + cswz * 8, As + (wave * 32 + q * 16) * 32);
      gld_lds16(Bg + (size_t)r * C_ + k0 + cswz * 8, Bs + (wave * 32 + q * 16) * 32);
    }
    __syncthreads();
    bf16x8 a[4], bv[4];
    #pragma unroll
    for (int mf = 0; mf < 4; ++mf) {
      int r = wm * 64 + mf * 16 + lr;
      a[mf] = *(const bf16x8*)(As + r * 32 + ((kg ^ (r & 3)) * 8));
    }
    #pragma unroll
    for (int nf = 0; nf < 4; ++nf) {
      int r = wn * 64 + nf * 16 + lr;
      bv[nf] = *(const bf16x8*)(Bs + r * 32 + ((kg ^ (r & 3)) * 8));
    }
    #pragma unroll
    for (int mf = 0; mf < 4; ++mf)
      #pragma unroll
      for (int nf = 0; nf < 4; ++nf)
        acc[mf][nf] = __builtin_amdgcn_mfma_f32_16x16x32_bf16(a[mf], bv[nf], acc[mf][nf], 0, 0, 0);
    __syncthreads();
  }
  u16* Og = qkv + (size_t)g * QKVC * N_;
  #pragma unroll
  for (int mf = 0; mf < 4; ++mf)
    #pragma unroll
    for (int nf = 0; nf < 4; ++nf)
      #pragma unroll
      for (int j = 0; j < 4; ++j) {
        int row = o0 + wm * 64 + mf * 16 + kg * 4 + j;
        int col = n0 + wn * 64 + nf * 16 + lr;
        Og[(size_t)row * N_ + col] = f2b(acc[mf][nf][j]);
      }
}

// ---------------- context partials via MFMA: P=exp(K), C_p[d][e] = sum_n P[d][n] V[e][n] ----------------
__global__ __launch_bounds__(256) void k_ctx2(const u16* __restrict__ qkv,
                                              float* __restrict__ ctxp) {
  constexpr int TK = 128;                       // n per staging tile
  __shared__ __align__(16) u16 Pl[64 * TK];     // 16KB, swizzled
  __shared__ __align__(16) u16 Vl[64 * TK];     // 16KB, swizzled
  int g = blockIdx.z, h = blockIdx.y, nc = blockIdx.x;
  int t = threadIdx.x, wave = t >> 6, lane = t & 63;
  int kg = lane >> 4, lr = lane & 15;
  const u16* Kg = qkv + ((size_t)g * QKVC + HID + h * DH) * N_;
  const u16* Vg = qkv + ((size_t)g * QKVC + 2 * HID + h * DH) * N_;

  f32x4 acc[4];
  #pragma unroll
  for (int nf = 0; nf < 4; ++nf) acc[nf] = (f32x4)0.f;
  float rsum[4] = {0.f, 0.f, 0.f, 0.f};

  for (int it = 0; it < 4; ++it) {
    int n0 = nc * 512 + it * TK;
    #pragma unroll
    for (int s = 0; s < 4; ++s) {
      int cid = t + 256 * s;
      int r = cid >> 4, cc = cid & 15;          // 64 rows x 16 chunks of 8
      union { bf16x8 v; u16 u[8]; } kv_, vv, pw;
      kv_.v = *(const bf16x8*)(Kg + (size_t)r * N_ + n0 + cc * 8);
      vv.v  = *(const bf16x8*)(Vg + (size_t)r * N_ + n0 + cc * 8);
      #pragma unroll
      for (int j = 0; j < 8; ++j) {
        float p = __expf(b2f(kv_.u[j]));
        rsum[s] += p;
        pw.u[j] = f2b(p);
      }
      *(bf16x8*)(Pl + r * TK + ((cc ^ (r & 15)) * 8)) = pw.v;
      *(bf16x8*)(Vl + r * TK + ((cc ^ (r & 15)) * 8)) = vv.v;
    }
    __syncthreads();
    #pragma unroll
    for (int k = 0; k < 4; ++k) {
      int c = k * 4 + kg;
      bf16x8 af = *(const bf16x8*)(Pl + (wave * 16 + lr) * TK + ((c ^ lr) * 8));
      #pragma unroll
      for (int nf = 0; nf < 4; ++nf) {
        bf16x8 bfv = *(const bf16x8*)(Vl + (nf * 16 + lr) * TK + ((c ^ lr) * 8));
        acc[nf] = __builtin_amdgcn_mfma_f32_16x16x32_bf16(af, bfv, acc[nf], 0, 0, 0);
      }
    }
    __syncthreads();
  }
  float* cgp = ctxp + ((size_t)(g * NH + h) * 8 + nc) * 4160;
  #pragma unroll
  for (int nf = 0; nf < 4; ++nf)
    #pragma unroll
    for (int j = 0; j < 4; ++j) {
      int d = wave * 16 + kg * 4 + j;
      int e = nf * 16 + lr;
      cgp[d * 64 + e] = acc[nf][j];
    }
  #pragma unroll
  for (int s = 0; s < 4; ++s) {
    #pragma unroll
    for (int m = 1; m < 16; m <<= 1) rsum[s] += __shfl_xor(rsum[s], m);
  }
  if (lr == 0) {
    #pragma unroll
    for (int s = 0; s < 4; ++s) cgp[4096 + (wave * 4 + kg + 16 * s)] = rsum[s];
  }
}

// ---------------- finalize context: sum partials + mem terms, /s_d, -> bf16 transposed [e][d] ----------------
__global__ __launch_bounds__(256) void k_cfin(const float* __restrict__ ctxp,
                                              const float* __restrict__ memkv,
                                              u16* __restrict__ ctxTb) {
  int g = blockIdx.y, h = blockIdx.x;
  int t = threadIdx.x;
  __shared__ float emk[DH * NMEM];
  __shared__ float sd[DH];
  const float* mk = memkv + (size_t)h * DH * NMEM;
  const float* mv = memkv + (size_t)(NH + h) * DH * NMEM;
  const float* cp = ctxp + (size_t)(g * NH + h) * 8 * 4160;
  emk[t] = __expf(mk[t]);                      // t = d*4+j
  __syncthreads();
  if (t < DH) {
    float s = 0.f;
    #pragma unroll
    for (int p = 0; p < 8; ++p) s += cp[p * 4160 + 4096 + t];
    #pragma unroll
    for (int j = 0; j < NMEM; ++j) s += emk[t * 4 + j];
    sd[t] = s;
  }
  __syncthreads();
  u16* ct = ctxTb + (size_t)(g * NH + h) * 4096;
  #pragma unroll
  for (int i = 0; i < 16; ++i) {
    int idx = t + 256 * i;
    int d = idx >> 6, e = idx & 63;
    float v = 0.f;
    #pragma unroll
    for (int p = 0; p < 8; ++p) v += cp[p * 4160 + idx];
    #pragma unroll
    for (int j = 0; j < NMEM; ++j) v += emk[d * 4 + j] * mv[e * 4 + j];
    ct[e * 64 + d] = f2b(v / sd[d]);           // transposed, bf16
  }
}

// ---------------- q-softmax + PV via MFMA -> attnT[g][n][hid] bf16 ----------------
__global__ __launch_bounds__(256) void k_pv(const u16* __restrict__ qkv,
                                            const u16* __restrict__ ctxTb,
                                            u16* __restrict__ attnT) {
  int g = blockIdx.z, h = blockIdx.y;
  int t = threadIdx.x, wave = t >> 6, lane = t & 63;
  int kg = lane >> 4, lr = lane & 15;
  int n0 = blockIdx.x * 256;
  __shared__ __align__(16) u16 qs[256 * 64];   // [n][d] swizzled, 32KB
  __shared__ __align__(16) u16 cl[64 * 64];    // [e][d] swizzled, 8KB

  {
    const u16* cg = ctxTb + (size_t)(g * NH + h) * 4096;
    #pragma unroll
    for (int i = 0; i < 2; ++i) {
      int id = t + 256 * i;          // 0..511
      int r = id >> 3, c = id & 7;
      *(bf16x8*)(cl + r * 64 + ((c ^ (r & 7)) * 8)) = *(const bf16x8*)(cg + r * 64 + c * 8);
    }
  }
  const u16* Qg = qkv + ((size_t)g * QKVC + (size_t)h * DH) * N_ + n0 + t;
  float q[64]; float s = 0.f;
  #pragma unroll
  for (int d = 0; d < DH; ++d) { q[d] = __expf(b2f(Qg[(size_t)d * N_])); s += q[d]; }
  float inv = 0.125f / s;
  #pragma unroll
  for (int c = 0; c < 8; ++c) {
    union { bf16x8 v; u16 u[8]; } pk;
    #pragma unroll
    for (int j = 0; j < 8; ++j) pk.u[j] = f2b(q[c * 8 + j] * inv);
    *(bf16x8*)(qs + t * 64 + ((c ^ (t & 7)) * 8)) = pk.v;
  }
  __syncthreads();

  f32x4 acc[4][4];
  #pragma unroll
  for (int i = 0; i < 4; ++i)
    #pragma unroll
    for (int j = 0; j < 4; ++j) acc[i][j] = (f32x4)0.f;

  #pragma unroll
  for (int ks = 0; ks < 2; ++ks) {
    bf16x8 a[4], bv[4];
    #pragma unroll
    for (int mf = 0; mf < 4; ++mf) {
      int r = wave * 64 + mf * 16 + lr;
      a[mf] = *(const bf16x8*)(qs + r * 64 + (((ks * 4 + kg) ^ (r & 7)) * 8));
    }
    #pragma unroll
    for (int nf = 0; nf < 4; ++nf) {
      int r = nf * 16 + lr;
      bv[nf] = *(const bf16x8*)(cl + r * 64 + (((ks * 4 + kg) ^ (r & 7)) * 8));
    }
    #pragma unroll
    for (int mf = 0; mf < 4; ++mf)
      #pragma unroll
      for (int nf = 0; nf < 4; ++nf)
        acc[mf][nf] = __builtin_amdgcn_mfma_f32_16x16x32_bf16(a[mf], bv[nf], acc[mf][nf], 0, 0, 0);
  }

  u16* op = attnT + ((size_t)g * N_ + n0) * HID + h * DH;
  #pragma unroll
  for (int mf = 0; mf < 4; ++mf)
    #pragma unroll
    for (int nf = 0; nf < 4; ++nf)
      #pragma unroll
      for (int j = 0; j < 4; ++j) {
        int n = wave * 64 + mf * 16 + kg * 4 + j;
        int e = nf * 16 + lr;
        op[(size_t)n * HID + e] = f2b(acc[mf][nf][j]);
      }
}

// ---------------- out-proj GEMM + bias + fused rmsnorm2, BN=128 ----------------
__global__ __launch_bounds__(256) void k_out(const u16* __restrict__ Wb,
                                             const u16* __restrict__ AT,
                                             const float* __restrict__ bias,
                                             const float* __restrict__ g2,
                                             float* __restrict__ out) {
  constexpr int BN = 128, BK = 32;
  __shared__ __align__(16) u16 As[256 * BK];   // 16KB
  __shared__ __align__(16) u16 Bs[BN * BK];    // 8KB
  __shared__ float part[4][BN];                // 2KB
  int g  = blockIdx.y;
  int n0 = blockIdx.x * BN;
  int t = threadIdx.x, wave = t >> 6, lane = t & 63;
  int kg = lane >> 4, lr = lane & 15;

  const u16* Bg = AT + ((size_t)g * N_ + n0) * HID;

  int rloc = lane >> 2;
  int cswz = (lane & 3) ^ (rloc & 3);

  f32x4 acc[4][8];
  #pragma unroll
  for (int i = 0; i < 4; ++i)
    #pragma unroll
    for (int j = 0; j < 8; ++j) acc[i][j] = (f32x4)0.f;

  for (int k0 = 0; k0 < HID; k0 += BK) {
    #pragma unroll
    for (int q = 0; q < 4; ++q) {
      int r = wave * 64 + q * 16 + rloc;
      gld_lds16(Wb + (size_t)r * HID + k0 + cswz * 8, As + (wave * 64 + q * 16) * 32);
    }
    #pragma unroll
    for (int q = 0; q < 2; ++q) {
      int r = wave * 32 + q * 16 + rloc;
      gld_lds16(Bg + (size_t)r * HID + k0 + cswz * 8, Bs + (wave * 32 + q * 16) * 32);
    }
    __syncthreads();
    bf16x8 a[4], bv[8];
    #pragma unroll
    for (int mf = 0; mf < 4; ++mf) {
      int r = wave * 64 + mf * 16 + lr;
      a[mf] = *(const bf16x8*)(As + r * 32 + ((kg ^ (r & 3)) * 8));
    }
    #pragma unroll
    for (int nf = 0; nf < 8; ++nf) {
      int r = nf * 16 + lr;
      bv[nf] = *(const bf16x8*)(Bs + r * 32 + ((kg ^ (r & 3)) * 8));
    }
    #pragma unroll
    for (int mf = 0; mf < 4; ++mf)
      #pragma unroll
      for (int nf = 0; nf < 8; ++nf)
        acc[mf][nf] = __builtin_amdgcn_mfma_f32_16x16x32_bf16(a[mf], bv[nf], acc[mf][nf], 0, 0, 0);
    __syncthreads();
  }
  float colsq[8] = {0.f, 0.f, 0.f, 0.f, 0.f, 0.f, 0.f, 0.f};
  #pragma unroll
  for (int mf = 0; mf < 4; ++mf)
    #pragma unroll
    for (int j = 0; j < 4; ++j) {
      int row = wave * 64 + mf * 16 + kg * 4 + j;
      float bs = bias[row];
      #pragma unroll
      for (int nf = 0; nf < 8; ++nf) {
        float v = acc[mf][nf][j] + bs;
        acc[mf][nf][j] = v;
        colsq[nf] += v * v;
      }
    }
  #pragma unroll
  for (int nf = 0; nf < 8; ++nf) {
    colsq[nf] += __shfl_xor(colsq[nf], 16);
    colsq[nf] += __shfl_xor(colsq[nf], 32);
  }
  if (kg == 0) {
    #pragma unroll
    for (int nf = 0; nf < 8; ++nf) part[wave][nf * 16 + lr] = colsq[nf];
  }
  __syncthreads();
  float* og = out + (size_t)g * C_ * N_ + n0;
  #pragma unroll
  for (int nf = 0; nf < 8; ++nf) {
    int col = nf * 16 + lr;
    float tot = part[0][col] + part[1][col] + part[2][col] + part[3][col];
    float invn = 16.0f / fmaxf(sqrtf(tot), 1e-12f);
    #pragma unroll
    for (int mf = 0; mf < 4; ++mf)
      #pragma unroll
      for (int j = 0; j < 4; ++j) {
        int row = wave * 64 + mf * 16 + kg * 4 + j;
        og[(size_t)row * N_ + col] = acc[mf][nf][j] * invn * g2[row];
      }
  }
}

extern "C" void kernel_launch(void* const* d_in, const int* in_sizes, int n_in,
                              void* d_out, int out_size, void* d_ws, size_t ws_size,
                              hipStream_t stream) {
  (void)in_sizes; (void)n_in; (void)out_size;
  const float* x      = (const float*)d_in[0];
  const float* gain1  = (const float*)d_in[1];
  const float* w_qkv  = (const float*)d_in[2];
  const float* mem_kv = (const float*)d_in[3];
  const float* w_out  = (const float*)d_in[4];
  const float* b_out  = (const float*)d_in[5];
  const float* gain2  = (const float*)d_in[6];
  float* out = (float*)d_out;

  char* ws = (char*)d_ws;
  u16* wqkvb = (u16*)ws;                         // 786,432 B
  u16* woutb = (u16*)(ws + 786432);              // 262,144 B
  size_t shared_b = 1048576;

  const size_t xbT_b   = (size_t)N_ * C_ * 2;          //  2 MiB
  const size_t qkv_b   = (size_t)QKVC * N_ * 2;        // 12 MiB
  const size_t attnT_b = (size_t)HID * N_ * 2;         //  4 MiB
  const size_t ctxp_b  = (size_t)NH * 8 * 4160 * 4;    // ~1.02 MiB
  const size_t ctxT_b  = (size_t)NH * 4096 * 2;        // 64 KiB
  const size_t per_b   = xbT_b + qkv_b + attnT_b + ctxp_b + ctxT_b;

  int G = 16;
  while (G > 1 && shared_b + (size_t)G * per_b > ws_size) G >>= 1;

  char* base = ws + shared_b;
  u16*   xbT   = (u16*)base;
  u16*   qkv   = (u16*)(base + (size_t)G * xbT_b);
  u16*   attnT = (u16*)(base + (size_t)G * (xbT_b + qkv_b));
  float* ctxp  = (float*)(base + (size_t)G * (xbT_b + qkv_b + attnT_b));
  u16*   ctxTb = (u16*)(base + (size_t)G * (xbT_b + qkv_b + attnT_b + ctxp_b));

  k_cvtw<<<256, 256, 0, stream>>>(w_qkv, w_out, wqkvb, woutb);

  for (int b0 = 0; b0 < B_; b0 += G) {
    const float* xc = x + (size_t)b0 * C_ * N_;
    float*       oc = out + (size_t)b0 * C_ * N_;
    k_rms1 <<<dim3(N_ / 256, G),      256, 0, stream>>>(xc, gain1, xbT);
    k_qkv  <<<dim3(12 * 32 * G),      256, 0, stream>>>(wqkvb, xbT, qkv);
    k_ctx2 <<<dim3(8, NH, G),         256, 0, stream>>>(qkv, ctxp);
    k_cfin <<<dim3(NH, G),            256, 0, stream>>>(ctxp, mem_kv, ctxTb);
    k_pv   <<<dim3(N_ / 256, NH, G),  256, 0, stream>>>(qkv, ctxTb, attnT);
    k_out  <<<dim3(N_ / 128, G),      256, 0, stream>>>(woutb, attnT, b_out, gain2, oc);
  }
}

// Round 7
// 244.903 us; speedup vs baseline: 3.0517x; 1.2415x over previous
//
#include <hip/hip_runtime.h>

typedef __attribute__((ext_vector_type(8))) short bf16x8;
typedef __attribute__((ext_vector_type(4))) float f32x4;
typedef unsigned short u16;

constexpr int B_   = 16;
constexpr int C_   = 256;
constexpr int NH   = 8;
constexpr int DH   = 64;
constexpr int NMEM = 4;
constexpr int HID  = 512;    // NH*DH
constexpr int QKVC = 1536;   // 3*HID
constexpr int N_   = 4096;   // 64*64

__device__ __forceinline__ u16 f2b(float f) {   // RNE f32->bf16
  union { float f; unsigned u; } v{f};
  unsigned r = v.u + 0x7fff + ((v.u >> 16) & 1);
  return (u16)(r >> 16);
}
__device__ __forceinline__ float b2f(u16 h) {
  union { unsigned u; float f; } v; v.u = ((unsigned)h) << 16; return v.f;
}

// async global->LDS, 16B per lane; lds dest = wave-uniform base + lane*16B
__device__ __forceinline__ void gld_lds16(const u16* g, u16* l) {
  __builtin_amdgcn_global_load_lds(
      (const __attribute__((address_space(1))) unsigned*)g,
      (__attribute__((address_space(3))) unsigned*)l, 16, 0, 0);
}

// ---------------- weights -> bf16 (once per call) ----------------
__global__ void k_cvtw(const float* __restrict__ wq, const float* __restrict__ wo,
                       u16* __restrict__ wqb, u16* __restrict__ wob) {
  int i = blockIdx.x * 256 + threadIdx.x;
  for (int idx = i; idx < QKVC * C_; idx += gridDim.x * 256) wqb[idx] = f2b(wq[idx]);
  for (int idx = i; idx < C_ * HID; idx += gridDim.x * 256) wob[idx] = f2b(wo[idx]);
}

// ---------------- rmsnorm1 + transpose to bf16 [g][n][c] ----------------
__global__ __launch_bounds__(256) void k_rms1(const float* __restrict__ x,
                                              const float* __restrict__ g1,
                                              u16* __restrict__ xbT) {
  int g = blockIdx.y;
  int n = blockIdx.x * 256 + threadIdx.x;
  const float* xp = x + (size_t)g * C_ * N_ + n;
  float ss = 0.f;
  #pragma unroll 8
  for (int c = 0; c < C_; ++c) { float v = xp[(size_t)c * N_]; ss += v * v; }
  float inv = 16.0f / fmaxf(sqrtf(ss), 1e-12f);
  u16* op = xbT + ((size_t)g * N_ + n) * C_;
  for (int c0 = 0; c0 < C_; c0 += 8) {
    union { bf16x8 v; u16 u[8]; } pk;
    #pragma unroll
    for (int j = 0; j < 8; ++j) pk.u[j] = f2b(xp[(size_t)(c0 + j) * N_] * inv * g1[c0 + j]);
    *(bf16x8*)(op + c0) = pk.v;
  }
}

// ---------------- KV GEMM: kv[g][o][n] = sum_c Wkv[o][c]*Xn[c][n]  (o: 0..1023 = K rows then V rows)
__global__ __launch_bounds__(256) void k_kv(const u16* __restrict__ Wb,
                                            const u16* __restrict__ XT,
                                            u16* __restrict__ kv) {
  constexpr int BK = 32;
  __shared__ __align__(16) u16 As[128 * BK];
  __shared__ __align__(16) u16 Bs[128 * BK];
  int cpx = gridDim.x >> 3;                 // nwg = 8ob*32nb*G, %8==0
  int bid = blockIdx.x;
  int L = (bid & 7) * cpx + (bid >> 3);
  int ob = L & 7, rest = L >> 3;
  int nb = rest & 31, g = rest >> 5;
  int o0 = ob * 128;
  int n0 = nb * 128;
  int t = threadIdx.x, wave = t >> 6, lane = t & 63;
  int wm = wave >> 1, wn = wave & 1;
  int kg = lane >> 4, lr = lane & 15;

  const u16* Ag = Wb + (size_t)(HID + o0) * C_;   // KV weight rows 512..1535
  const u16* Bg = XT + ((size_t)g * N_ + n0) * C_;

  int rloc = lane >> 2;
  int cswz = (lane & 3) ^ (rloc & 3);

  f32x4 acc[4][4];
  #pragma unroll
  for (int i = 0; i < 4; ++i)
    #pragma unroll
    for (int j = 0; j < 4; ++j) acc[i][j] = (f32x4)0.f;

  for (int k0 = 0; k0 < C_; k0 += BK) {
    #pragma unroll
    for (int q = 0; q < 2; ++q) {
      int r = wave * 32 + q * 16 + rloc;
      gld_lds16(Ag + (size_t)r * C_ + k0 + cswz * 8, As + (wave * 32 + q * 16) * 32);
      gld_lds16(Bg + (size_t)r * C_ + k0 + cswz * 8, Bs + (wave * 32 + q * 16) * 32);
    }
    __syncthreads();
    bf16x8 a[4], bv[4];
    #pragma unroll
    for (int mf = 0; mf < 4; ++mf) {
      int r = wm * 64 + mf * 16 + lr;
      a[mf] = *(const bf16x8*)(As + r * 32 + ((kg ^ (r & 3)) * 8));
    }
    #pragma unroll
    for (int nf = 0; nf < 4; ++nf) {
      int r = wn * 64 + nf * 16 + lr;
      bv[nf] = *(const bf16x8*)(Bs + r * 32 + ((kg ^ (r & 3)) * 8));
    }
    #pragma unroll
    for (int mf = 0; mf < 4; ++mf)
      #pragma unroll
      for (int nf = 0; nf < 4; ++nf)
        acc[mf][nf] = __builtin_amdgcn_mfma_f32_16x16x32_bf16(a[mf], bv[nf], acc[mf][nf], 0, 0, 0);
    __syncthreads();
  }
  u16* Og = kv + (size_t)g * 1024 * N_;
  #pragma unroll
  for (int mf = 0; mf < 4; ++mf)
    #pragma unroll
    for (int nf = 0; nf < 4; ++nf)
      #pragma unroll
      for (int j = 0; j < 4; ++j) {
        int row = o0 + wm * 64 + mf * 16 + kg * 4 + j;
        int col = n0 + wn * 64 + nf * 16 + lr;
        Og[(size_t)row * N_ + col] = f2b(acc[mf][nf][j]);
      }
}

// ---------------- context partials via MFMA: P=exp(K), C_p[d][e] = sum_n P[d][n] V[e][n] ----------------
__global__ __launch_bounds__(256) void k_ctx2(const u16* __restrict__ kv,
                                              float* __restrict__ ctxp) {
  constexpr int TK = 128;
  __shared__ __align__(16) u16 Pl[64 * TK];
  __shared__ __align__(16) u16 Vl[64 * TK];
  int g = blockIdx.z, h = blockIdx.y, nc = blockIdx.x;
  int t = threadIdx.x, wave = t >> 6, lane = t & 63;
  int kg = lane >> 4, lr = lane & 15;
  const u16* Kg = kv + ((size_t)g * 1024 + h * DH) * N_;
  const u16* Vg = kv + ((size_t)g * 1024 + 512 + h * DH) * N_;

  f32x4 acc[4];
  #pragma unroll
  for (int nf = 0; nf < 4; ++nf) acc[nf] = (f32x4)0.f;
  float rsum[4] = {0.f, 0.f, 0.f, 0.f};

  for (int it = 0; it < 4; ++it) {
    int n0 = nc * 512 + it * TK;
    #pragma unroll
    for (int s = 0; s < 4; ++s) {
      int cid = t + 256 * s;
      int r = cid >> 4, cc = cid & 15;
      union { bf16x8 v; u16 u[8]; } kv_, vv, pw;
      kv_.v = *(const bf16x8*)(Kg + (size_t)r * N_ + n0 + cc * 8);
      vv.v  = *(const bf16x8*)(Vg + (size_t)r * N_ + n0 + cc * 8);
      #pragma unroll
      for (int j = 0; j < 8; ++j) {
        float p = __expf(b2f(kv_.u[j]));
        rsum[s] += p;
        pw.u[j] = f2b(p);
      }
      *(bf16x8*)(Pl + r * TK + ((cc ^ (r & 15)) * 8)) = pw.v;
      *(bf16x8*)(Vl + r * TK + ((cc ^ (r & 15)) * 8)) = vv.v;
    }
    __syncthreads();
    #pragma unroll
    for (int k = 0; k < 4; ++k) {
      int c = k * 4 + kg;
      bf16x8 af = *(const bf16x8*)(Pl + (wave * 16 + lr) * TK + ((c ^ lr) * 8));
      #pragma unroll
      for (int nf = 0; nf < 4; ++nf) {
        bf16x8 bfv = *(const bf16x8*)(Vl + (nf * 16 + lr) * TK + ((c ^ lr) * 8));
        acc[nf] = __builtin_amdgcn_mfma_f32_16x16x32_bf16(af, bfv, acc[nf], 0, 0, 0);
      }
    }
    __syncthreads();
  }
  float* cgp = ctxp + ((size_t)(g * NH + h) * 8 + nc) * 4160;
  #pragma unroll
  for (int nf = 0; nf < 4; ++nf)
    #pragma unroll
    for (int j = 0; j < 4; ++j) {
      int d = wave * 16 + kg * 4 + j;
      int e = nf * 16 + lr;
      cgp[d * 64 + e] = acc[nf][j];
    }
  #pragma unroll
  for (int s = 0; s < 4; ++s) {
    #pragma unroll
    for (int m = 1; m < 16; m <<= 1) rsum[s] += __shfl_xor(rsum[s], m);
  }
  if (lr == 0) {
    #pragma unroll
    for (int s = 0; s < 4; ++s) cgp[4096 + (wave * 4 + kg + 16 * s)] = rsum[s];
  }
}

// ---------------- finalize context: sum partials + mem terms, /s_d, -> bf16 transposed [e][d] ----------------
__global__ __launch_bounds__(256) void k_cfin(const float* __restrict__ ctxp,
                                              const float* __restrict__ memkv,
                                              u16* __restrict__ ctxTb) {
  int g = blockIdx.y, h = blockIdx.x;
  int t = threadIdx.x;
  __shared__ float emk[DH * NMEM];
  __shared__ float sd[DH];
  const float* mk = memkv + (size_t)h * DH * NMEM;
  const float* mv = memkv + (size_t)(NH + h) * DH * NMEM;
  const float* cp = ctxp + (size_t)(g * NH + h) * 8 * 4160;
  emk[t] = __expf(mk[t]);                      // t = d*4+j
  __syncthreads();
  if (t < DH) {
    float s = 0.f;
    #pragma unroll
    for (int p = 0; p < 8; ++p) s += cp[p * 4160 + 4096 + t];
    #pragma unroll
    for (int j = 0; j < NMEM; ++j) s += emk[t * 4 + j];
    sd[t] = s;
  }
  __syncthreads();
  u16* ct = ctxTb + (size_t)(g * NH + h) * 4096;
  #pragma unroll
  for (int i = 0; i < 16; ++i) {
    int idx = t + 256 * i;
    int d = idx >> 6, e = idx & 63;
    float v = 0.f;
    #pragma unroll
    for (int p = 0; p < 8; ++p) v += cp[p * 4160 + idx];
    #pragma unroll
    for (int j = 0; j < NMEM; ++j) v += emk[d * 4 + j] * mv[e * 4 + j];
    ct[e * 64 + d] = f2b(v / sd[d]);           // transposed, bf16
  }
}

// ---------------- fused Q-GEMM + q-softmax + PV -> attnT[g][n][hid] bf16 ----------------
// Per block: head-pair hh, n-chunk 128. Phase A: Q=Wq@X (128 rows = 2 heads).
// Phase B: softmax over d per column on f32 acc (wave-local), bf16 -> swizzled LDS [n][d].
// Phase C: out[n][e] = sum_d qsm[n][d]*ctxT[e][d] via MFMA, store attnT.
__global__ __launch_bounds__(256) void k_qpv(const u16* __restrict__ Wq,
                                             const u16* __restrict__ XT,
                                             const u16* __restrict__ ctxTb,
                                             u16* __restrict__ attnT) {
  constexpr int BK = 32;
  __shared__ __align__(16) u16 smem[24576];    // 48KB
  u16* Ws = smem;                               // [0, 8KB)
  u16* Xs = smem + 4096;                        // [8KB, 16KB)
  // qsm aliases [0, 32KB) after phase A; cl at [32KB, 48KB)
  u16* cl = smem + 16384;

  int cpx = gridDim.x >> 3;                    // nwg = 4hh*32nc*G, %8==0
  int bid = blockIdx.x;
  int L = (bid & 7) * cpx + (bid >> 3);
  int hh = L & 3, rest = L >> 2;
  int nc = rest & 31, g = rest >> 5;
  int t = threadIdx.x, wave = t >> 6, lane = t & 63;
  int wm = wave >> 1, wn = wave & 1;
  int kg = lane >> 4, lr = lane & 15;

  // stage ctxT for both heads (16KB), swizzled like k_pv's cl
  {
    const u16* cg = ctxTb + (size_t)(g * NH + hh * 2) * 4096;
    #pragma unroll
    for (int i = 0; i < 4; ++i) {
      int id = t + 256 * i;                    // 0..1023 chunks of 8
      int r = id >> 3, c = id & 7;             // r: 0..127 (head = r>>6, e = r&63)
      *(bf16x8*)(cl + (r >> 6) * 4096 + (r & 63) * 64 + ((c ^ (r & 7)) * 8)) =
          *(const bf16x8*)(cg + id * 8);
    }
  }

  const u16* Ag = Wq + (size_t)(hh * 128) * C_;
  const u16* Bg = XT + ((size_t)g * N_ + nc * 128) * C_;
  int rloc = lane >> 2;
  int cswz = (lane & 3) ^ (rloc & 3);

  f32x4 acc[4][4];
  #pragma unroll
  for (int i = 0; i < 4; ++i)
    #pragma unroll
    for (int j = 0; j < 4; ++j) acc[i][j] = (f32x4)0.f;

  for (int k0 = 0; k0 < C_; k0 += BK) {
    #pragma unroll
    for (int q = 0; q < 2; ++q) {
      int r = wave * 32 + q * 16 + rloc;
      gld_lds16(Ag + (size_t)r * C_ + k0 + cswz * 8, Ws + (wave * 32 + q * 16) * 32);
      gld_lds16(Bg + (size_t)r * C_ + k0 + cswz * 8, Xs + (wave * 32 + q * 16) * 32);
    }
    __syncthreads();
    bf16x8 a[4], bv[4];
    #pragma unroll
    for (int mf = 0; mf < 4; ++mf) {
      int r = wm * 64 + mf * 16 + lr;
      a[mf] = *(const bf16x8*)(Ws + r * 32 + ((kg ^ (r & 3)) * 8));
    }
    #pragma unroll
    for (int nf = 0; nf < 4; ++nf) {
      int r = wn * 64 + nf * 16 + lr;
      bv[nf] = *(const bf16x8*)(Xs + r * 32 + ((kg ^ (r & 3)) * 8));
    }
    #pragma unroll
    for (int mf = 0; mf < 4; ++mf)
      #pragma unroll
      for (int nf = 0; nf < 4; ++nf)
        acc[mf][nf] = __builtin_amdgcn_mfma_f32_16x16x32_bf16(a[mf], bv[nf], acc[mf][nf], 0, 0, 0);
    __syncthreads();
  }

  // ---- phase B: softmax over d (rows of this wm-half = one head), per column n ----
  float colsum[4];
  #pragma unroll
  for (int nf = 0; nf < 4; ++nf) {
    float s = 0.f;
    #pragma unroll
    for (int mf = 0; mf < 4; ++mf)
      #pragma unroll
      for (int j = 0; j < 4; ++j) {
        float e = __expf(acc[mf][nf][j]);
        acc[mf][nf][j] = e;
        s += e;
      }
    colsum[nf] = s;
  }
  #pragma unroll
  for (int nf = 0; nf < 4; ++nf) {
    colsum[nf] += __shfl_xor(colsum[nf], 16);   // across kg (rows)
    colsum[nf] += __shfl_xor(colsum[nf], 32);
  }
  u16* qh = smem + wm * 8192;                   // qsm for head wm: [128 n][64 d] swizzled
  #pragma unroll
  for (int nf = 0; nf < 4; ++nf) {
    float invs = 0.125f / colsum[nf];
    int n = wn * 64 + nf * 16 + lr;
    #pragma unroll
    for (int mf = 0; mf < 4; ++mf)
      #pragma unroll
      for (int jp = 0; jp < 2; ++jp) {
        int d0 = mf * 16 + kg * 4 + jp * 2;
        u16 lo = f2b(acc[mf][nf][jp * 2] * invs);
        u16 hi = f2b(acc[mf][nf][jp * 2 + 1] * invs);
        unsigned pk = (unsigned)lo | ((unsigned)hi << 16);
        int idx = n * 64 + (((d0 >> 3) ^ (n & 7)) * 8) + (d0 & 7);
        *(unsigned*)(qh + idx) = pk;
      }
  }
  __syncthreads();

  // ---- phase C: PV MFMA. wave = (head hcl, n-half nh2) ----
  int hcl = wave >> 1, nh2 = wave & 1;
  const u16* qh2 = smem + hcl * 8192;
  const u16* clh = cl + hcl * 4096;
  f32x4 acc2[4][4];
  #pragma unroll
  for (int i = 0; i < 4; ++i)
    #pragma unroll
    for (int j = 0; j < 4; ++j) acc2[i][j] = (f32x4)0.f;

  #pragma unroll
  for (int kk = 0; kk < 2; ++kk) {
    int c = kk * 4 + kg;
    bf16x8 a2[4], b2[4];
    #pragma unroll
    for (int mf = 0; mf < 4; ++mf) {
      int rn = nh2 * 64 + mf * 16 + lr;
      a2[mf] = *(const bf16x8*)(qh2 + rn * 64 + ((c ^ (rn & 7)) * 8));
    }
    #pragma unroll
    for (int nf = 0; nf < 4; ++nf) {
      int re = nf * 16 + lr;
      b2[nf] = *(const bf16x8*)(clh + re * 64 + ((c ^ (re & 7)) * 8));
    }
    #pragma unroll
    for (int mf = 0; mf < 4; ++mf)
      #pragma unroll
      for (int nf = 0; nf < 4; ++nf)
        acc2[mf][nf] = __builtin_amdgcn_mfma_f32_16x16x32_bf16(a2[mf], b2[nf], acc2[mf][nf], 0, 0, 0);
  }

  int h = hh * 2 + hcl;
  u16* op = attnT + ((size_t)g * N_ + nc * 128) * HID + h * 64;
  #pragma unroll
  for (int mf = 0; mf < 4; ++mf)
    #pragma unroll
    for (int nf = 0; nf < 4; ++nf)
      #pragma unroll
      for (int j = 0; j < 4; ++j) {
        int n = nh2 * 64 + mf * 16 + kg * 4 + j;
        int e = nf * 16 + lr;
        op[(size_t)n * HID + e] = f2b(acc2[mf][nf][j]);
      }
}

// ---------------- out-proj GEMM + bias + fused rmsnorm2, BN=128 ----------------
__global__ __launch_bounds__(256) void k_out(const u16* __restrict__ Wb,
                                             const u16* __restrict__ AT,
                                             const float* __restrict__ bias,
                                             const float* __restrict__ g2,
                                             float* __restrict__ out) {
  constexpr int BN = 128, BK = 32;
  __shared__ __align__(16) u16 As[256 * BK];   // 16KB
  __shared__ __align__(16) u16 Bs[BN * BK];    // 8KB
  __shared__ float part[4][BN];                // 2KB
  int g  = blockIdx.y;
  int n0 = blockIdx.x * BN;
  int t = threadIdx.x, wave = t >> 6, lane = t & 63;
  int kg = lane >> 4, lr = lane & 15;

  const u16* Bg = AT + ((size_t)g * N_ + n0) * HID;

  int rloc = lane >> 2;
  int cswz = (lane & 3) ^ (rloc & 3);

  f32x4 acc[4][8];
  #pragma unroll
  for (int i = 0; i < 4; ++i)
    #pragma unroll
    for (int j = 0; j < 8; ++j) acc[i][j] = (f32x4)0.f;

  for (int k0 = 0; k0 < HID; k0 += BK) {
    #pragma unroll
    for (int q = 0; q < 4; ++q) {
      int r = wave * 64 + q * 16 + rloc;
      gld_lds16(Wb + (size_t)r * HID + k0 + cswz * 8, As + (wave * 64 + q * 16) * 32);
    }
    #pragma unroll
    for (int q = 0; q < 2; ++q) {
      int r = wave * 32 + q * 16 + rloc;
      gld_lds16(Bg + (size_t)r * HID + k0 + cswz * 8, Bs + (wave * 32 + q * 16) * 32);
    }
    __syncthreads();
    bf16x8 a[4], bv[8];
    #pragma unroll
    for (int mf = 0; mf < 4; ++mf) {
      int r = wave * 64 + mf * 16 + lr;
      a[mf] = *(const bf16x8*)(As + r * 32 + ((kg ^ (r & 3)) * 8));
    }
    #pragma unroll
    for (int nf = 0; nf < 8; ++nf) {
      int r = nf * 16 + lr;
      bv[nf] = *(const bf16x8*)(Bs + r * 32 + ((kg ^ (r & 3)) * 8));
    }
    #pragma unroll
    for (int mf = 0; mf < 4; ++mf)
      #pragma unroll
      for (int nf = 0; nf < 8; ++nf)
        acc[mf][nf] = __builtin_amdgcn_mfma_f32_16x16x32_bf16(a[mf], bv[nf], acc[mf][nf], 0, 0, 0);
    __syncthreads();
  }
  float colsq[8] = {0.f, 0.f, 0.f, 0.f, 0.f, 0.f, 0.f, 0.f};
  #pragma unroll
  for (int mf = 0; mf < 4; ++mf)
    #pragma unroll
    for (int j = 0; j < 4; ++j) {
      int row = wave * 64 + mf * 16 + kg * 4 + j;
      float bs = bias[row];
      #pragma unroll
      for (int nf = 0; nf < 8; ++nf) {
        float v = acc[mf][nf][j] + bs;
        acc[mf][nf][j] = v;
        colsq[nf] += v * v;
      }
    }
  #pragma unroll
  for (int nf = 0; nf < 8; ++nf) {
    colsq[nf] += __shfl_xor(colsq[nf], 16);
    colsq[nf] += __shfl_xor(colsq[nf], 32);
  }
  if (kg == 0) {
    #pragma unroll
    for (int nf = 0; nf < 8; ++nf) part[wave][nf * 16 + lr] = colsq[nf];
  }
  __syncthreads();
  float* og = out + (size_t)g * C_ * N_ + n0;
  #pragma unroll
  for (int nf = 0; nf < 8; ++nf) {
    int col = nf * 16 + lr;
    float tot = part[0][col] + part[1][col] + part[2][col] + part[3][col];
    float invn = 16.0f / fmaxf(sqrtf(tot), 1e-12f);
    #pragma unroll
    for (int mf = 0; mf < 4; ++mf)
      #pragma unroll
      for (int j = 0; j < 4; ++j) {
        int row = wave * 64 + mf * 16 + kg * 4 + j;
        og[(size_t)row * N_ + col] = acc[mf][nf][j] * invn * g2[row];
      }
  }
}

extern "C" void kernel_launch(void* const* d_in, const int* in_sizes, int n_in,
                              void* d_out, int out_size, void* d_ws, size_t ws_size,
                              hipStream_t stream) {
  (void)in_sizes; (void)n_in; (void)out_size;
  const float* x      = (const float*)d_in[0];
  const float* gain1  = (const float*)d_in[1];
  const float* w_qkv  = (const float*)d_in[2];
  const float* mem_kv = (const float*)d_in[3];
  const float* w_out  = (const float*)d_in[4];
  const float* b_out  = (const float*)d_in[5];
  const float* gain2  = (const float*)d_in[6];
  float* out = (float*)d_out;

  char* ws = (char*)d_ws;
  u16* wqkvb = (u16*)ws;                         // 786,432 B
  u16* woutb = (u16*)(ws + 786432);              // 262,144 B
  size_t shared_b = 1048576;

  const size_t xbT_b   = (size_t)N_ * C_ * 2;          //  2 MiB
  const size_t kv_b    = (size_t)1024 * N_ * 2;        //  8 MiB (K rows 0..511, V rows 512..1023)
  const size_t attnT_b = (size_t)HID * N_ * 2;         //  4 MiB
  const size_t ctxp_b  = (size_t)NH * 8 * 4160 * 4;    // ~1.02 MiB
  const size_t ctxT_b  = (size_t)NH * 4096 * 2;        // 64 KiB
  const size_t per_b   = xbT_b + kv_b + attnT_b + ctxp_b + ctxT_b;

  int G = 16;
  while (G > 1 && shared_b + (size_t)G * per_b > ws_size) G >>= 1;

  char* base = ws + shared_b;
  u16*   xbT   = (u16*)base;
  u16*   kv    = (u16*)(base + (size_t)G * xbT_b);
  u16*   attnT = (u16*)(base + (size_t)G * (xbT_b + kv_b));
  float* ctxp  = (float*)(base + (size_t)G * (xbT_b + kv_b + attnT_b));
  u16*   ctxTb = (u16*)(base + (size_t)G * (xbT_b + kv_b + attnT_b + ctxp_b));

  k_cvtw<<<256, 256, 0, stream>>>(w_qkv, w_out, wqkvb, woutb);

  for (int b0 = 0; b0 < B_; b0 += G) {
    const float* xc = x + (size_t)b0 * C_ * N_;
    float*       oc = out + (size_t)b0 * C_ * N_;
    k_rms1 <<<dim3(N_ / 256, G),     256, 0, stream>>>(xc, gain1, xbT);
    k_kv   <<<dim3(8 * 32 * G),      256, 0, stream>>>(wqkvb, xbT, kv);
    k_ctx2 <<<dim3(8, NH, G),        256, 0, stream>>>(kv, ctxp);
    k_cfin <<<dim3(NH, G),           256, 0, stream>>>(ctxp, mem_kv, ctxTb);
    k_qpv  <<<dim3(4 * 32 * G),      256, 0, stream>>>(wqkvb, xbT, ctxTb, attnT);
    k_out  <<<dim3(N_ / 128, G),     256, 0, stream>>>(woutb, attnT, b_out, gain2, oc);
  }
}

// Round 8
// 199.394 us; speedup vs baseline: 3.7482x; 1.2282x over previous
//
#include <hip/hip_runtime.h>

typedef __attribute__((ext_vector_type(8))) short bf16x8;
typedef __attribute__((ext_vector_type(4))) short bf16x4;
typedef __attribute__((ext_vector_type(4))) float f32x4;
typedef unsigned short u16;

constexpr int B_   = 16;
constexpr int C_   = 256;
constexpr int NH   = 8;
constexpr int DH   = 64;
constexpr int NMEM = 4;
constexpr int HID  = 512;    // NH*DH
constexpr int QKVC = 1536;   // 3*HID
constexpr int N_   = 4096;   // 64*64
constexpr int CTXS = 4224;   // per-nc ctxp stride: 4096 ctx + 128 rsum slots

__device__ __forceinline__ u16 f2b(float f) {   // RNE f32->bf16
  union { float f; unsigned u; } v{f};
  unsigned r = v.u + 0x7fff + ((v.u >> 16) & 1);
  return (u16)(r >> 16);
}
__device__ __forceinline__ float b2f(u16 h) {
  union { unsigned u; float f; } v; v.u = ((unsigned)h) << 16; return v.f;
}

// async global->LDS, 16B per lane; lds dest = wave-uniform base + lane*16B
__device__ __forceinline__ void gld_lds16(const u16* g, u16* l) {
  __builtin_amdgcn_global_load_lds(
      (const __attribute__((address_space(1))) unsigned*)g,
      (__attribute__((address_space(3))) unsigned*)l, 16, 0, 0);
}

// ---------------- weights -> bf16 (once per call) ----------------
__global__ void k_cvtw(const float* __restrict__ wq, const float* __restrict__ wo,
                       u16* __restrict__ wqb, u16* __restrict__ wob) {
  int i = blockIdx.x * 256 + threadIdx.x;
  for (int idx = i; idx < QKVC * C_; idx += gridDim.x * 256) wqb[idx] = f2b(wq[idx]);
  for (int idx = i; idx < C_ * HID; idx += gridDim.x * 256) wob[idx] = f2b(wo[idx]);
}

// ---------------- rmsnorm1 + transpose to bf16 [g][n][c] ----------------
__global__ __launch_bounds__(256) void k_rms1(const float* __restrict__ x,
                                              const float* __restrict__ g1,
                                              u16* __restrict__ xbT) {
  int g = blockIdx.y;
  int n = blockIdx.x * 256 + threadIdx.x;
  const float* xp = x + (size_t)g * C_ * N_ + n;
  float ss = 0.f;
  #pragma unroll 8
  for (int c = 0; c < C_; ++c) { float v = xp[(size_t)c * N_]; ss += v * v; }
  float inv = 16.0f / fmaxf(sqrtf(ss), 1e-12f);
  u16* op = xbT + ((size_t)g * N_ + n) * C_;
  for (int c0 = 0; c0 < C_; c0 += 8) {
    union { bf16x8 v; u16 u[8]; } pk;
    #pragma unroll
    for (int j = 0; j < 8; ++j) pk.u[j] = f2b(xp[(size_t)(c0 + j) * N_] * inv * g1[c0 + j]);
    *(bf16x8*)(op + c0) = pk.v;
  }
}

// ---------------- fused KV-GEMM + exp + PV-accumulate: kv tiles never hit HBM ----------------
// block (g,h,nc): for 4 tiles of 128 n: [K;V](128 o) x X(128 n) GEMM (operand-swapped:
// output row = n), epilogue -> Pl=exp(K), Vl=V in swizzled LDS, then ctx2-style PV MFMA
// accumulating ctx[d][e] partial over 512 n. Writes ctx partial + per-half P row-sums.
__global__ __launch_bounds__(256) void k_kvctx(const u16* __restrict__ Wb,
                                               const u16* __restrict__ XT,
                                               float* __restrict__ ctxp) {
  constexpr int BK = 32;
  __shared__ __align__(16) u16 smem[16384];    // 32 KB
  u16* Ws = smem;                               // [0,8K)B 128x32 staging (W rows: K64,V64)
  u16* Xs = smem + 4096;                        // [8K,16K)B 128x32 staging (X rows)
  u16* Pl = smem;                               // [0,16K)B  64x128 exp(K), aliases staging
  u16* Vl = smem + 8192;                        // [16K,32K)B 64x128 V

  int cpx = gridDim.x >> 3;                    // nwg = 64*G, %8==0
  int bid = blockIdx.x;
  int L = (bid & 7) * cpx + (bid >> 3);
  int h = L & 7, nc = (L >> 3) & 7, g = L >> 6;   // h innermost: X tile L2-hot across h
  int t = threadIdx.x, wave = t >> 6, lane = t & 63;
  int wm = wave >> 1, wn = wave & 1;           // wm: n-half, wn: 0=K half, 1=V half
  int kg = lane >> 4, lr = lane & 15;

  const u16* WK = Wb + (size_t)(HID + h * DH) * C_;
  const u16* WV = Wb + (size_t)(2 * HID + h * DH) * C_;
  const u16* Xg = XT + ((size_t)g * N_ + nc * 512) * C_;

  int rloc = lane >> 2;
  int cswz = (lane & 3) ^ (rloc & 3);
  // wave's staging rows: wave*32 + q*16 + rloc; W source uniform per wave (K for 0,1; V for 2,3)
  const u16* Wsrc = (wave < 2) ? WK : WV;
  int wrow0 = (wave * 32) & 63;                 // row offset within K- or V-range

  f32x4 acc2[4];
  #pragma unroll
  for (int nf = 0; nf < 4; ++nf) acc2[nf] = (f32x4)0.f;
  float rs[4] = {0.f, 0.f, 0.f, 0.f};

  for (int it = 0; it < 4; ++it) {
    f32x4 acc[4][4];
    #pragma unroll
    for (int i = 0; i < 4; ++i)
      #pragma unroll
      for (int j = 0; j < 4; ++j) acc[i][j] = (f32x4)0.f;

    for (int k0 = 0; k0 < C_; k0 += BK) {
      #pragma unroll
      for (int q = 0; q < 2; ++q) {
        int rw = wrow0 + q * 16 + rloc;
        int rx = wave * 32 + q * 16 + rloc;
        gld_lds16(Wsrc + (size_t)rw * C_ + k0 + cswz * 8, Ws + (wave * 32 + q * 16) * 32);
        gld_lds16(Xg + (size_t)(it * 128 + rx) * C_ + k0 + cswz * 8, Xs + (wave * 32 + q * 16) * 32);
      }
      __syncthreads();
      bf16x8 a[4], bv[4];
      #pragma unroll
      for (int mf = 0; mf < 4; ++mf) {        // A = X rows (n)
        int r = wm * 64 + mf * 16 + lr;
        a[mf] = *(const bf16x8*)(Xs + r * 32 + ((kg ^ (r & 3)) * 8));
      }
      #pragma unroll
      for (int nf = 0; nf < 4; ++nf) {        // B = W rows (o: d or e)
        int r = wn * 64 + nf * 16 + lr;
        bv[nf] = *(const bf16x8*)(Ws + r * 32 + ((kg ^ (r & 3)) * 8));
      }
      #pragma unroll
      for (int mf = 0; mf < 4; ++mf)
        #pragma unroll
        for (int nf = 0; nf < 4; ++nf)
          acc[mf][nf] = __builtin_amdgcn_mfma_f32_16x16x32_bf16(a[mf], bv[nf], acc[mf][nf], 0, 0, 0);
      __syncthreads();
    }

    // epilogue: lane value (mf,nf,j): n = wm*64+mf*16+kg*4+j (row), o = nf*16+lr (col)
    // K waves (wn==0): Pl[d][n] = exp(val) bf16, rsum; V waves: Vl[e][n] = val bf16
    if (wn == 0) {
      #pragma unroll
      for (int mf = 0; mf < 4; ++mf) {
        int nb = wm * 64 + mf * 16 + kg * 4;
        int cc = nb >> 3, off = nb & 7;        // off in {0,4}
        #pragma unroll
        for (int nf = 0; nf < 4; ++nf) {
          int d = nf * 16 + lr;
          float e0 = __expf(acc[mf][nf][0]);
          float e1 = __expf(acc[mf][nf][1]);
          float e2 = __expf(acc[mf][nf][2]);
          float e3 = __expf(acc[mf][nf][3]);
          rs[nf] += (e0 + e1) + (e2 + e3);
          union { bf16x4 v; u16 u[4]; } pk;
          pk.u[0] = f2b(e0); pk.u[1] = f2b(e1); pk.u[2] = f2b(e2); pk.u[3] = f2b(e3);
          *(bf16x4*)(Pl + d * 128 + ((cc ^ (d & 15)) * 8) + off) = pk.v;
        }
      }
    } else {
      #pragma unroll
      for (int mf = 0; mf < 4; ++mf) {
        int nb = wm * 64 + mf * 16 + kg * 4;
        int cc = nb >> 3, off = nb & 7;
        #pragma unroll
        for (int nf = 0; nf < 4; ++nf) {
          int e = nf * 16 + lr;
          union { bf16x4 v; u16 u[4]; } pk;
          pk.u[0] = f2b(acc[mf][nf][0]); pk.u[1] = f2b(acc[mf][nf][1]);
          pk.u[2] = f2b(acc[mf][nf][2]); pk.u[3] = f2b(acc[mf][nf][3]);
          *(bf16x4*)(Vl + e * 128 + ((cc ^ (e & 15)) * 8) + off) = pk.v;
        }
      }
    }
    __syncthreads();

    // PV MFMA (ctx2 verbatim): wave owns 16 d-rows; K-dim = 128 n of this tile
    #pragma unroll
    for (int k = 0; k < 4; ++k) {
      int c = k * 4 + kg;
      bf16x8 af = *(const bf16x8*)(Pl + (wave * 16 + lr) * 128 + ((c ^ lr) * 8));
      #pragma unroll
      for (int nf = 0; nf < 4; ++nf) {
        bf16x8 bfv = *(const bf16x8*)(Vl + (nf * 16 + lr) * 128 + ((c ^ lr) * 8));
        acc2[nf] = __builtin_amdgcn_mfma_f32_16x16x32_bf16(af, bfv, acc2[nf], 0, 0, 0);
      }
    }
    __syncthreads();
  }

  float* cgp = ctxp + ((size_t)(g * NH + h) * 8 + nc) * CTXS;
  #pragma unroll
  for (int nf = 0; nf < 4; ++nf)
    #pragma unroll
    for (int j = 0; j < 4; ++j) {
      int d = wave * 16 + kg * 4 + j;
      int e = nf * 16 + lr;
      cgp[d * 64 + e] = acc2[nf][j];
    }
  if (wn == 0) {                               // P row-sum partials (per wm-half)
    #pragma unroll
    for (int nf = 0; nf < 4; ++nf) {
      rs[nf] += __shfl_xor(rs[nf], 16);
      rs[nf] += __shfl_xor(rs[nf], 32);
    }
    if (lane < 16) {
      #pragma unroll
      for (int nf = 0; nf < 4; ++nf)
        cgp[4096 + wm * 64 + nf * 16 + lane] = rs[nf];
    }
  }
}

// ---------------- finalize context: sum partials + mem terms, /s_d, -> bf16 transposed [e][d] ----------------
__global__ __launch_bounds__(256) void k_cfin(const float* __restrict__ ctxp,
                                              const float* __restrict__ memkv,
                                              u16* __restrict__ ctxTb) {
  int g = blockIdx.y, h = blockIdx.x;
  int t = threadIdx.x;
  __shared__ float emk[DH * NMEM];
  __shared__ float sd[DH];
  const float* mk = memkv + (size_t)h * DH * NMEM;
  const float* mv = memkv + (size_t)(NH + h) * DH * NMEM;
  const float* cp = ctxp + (size_t)(g * NH + h) * 8 * CTXS;
  emk[t] = __expf(mk[t]);                      // t = d*4+j
  __syncthreads();
  if (t < DH) {
    float s = 0.f;
    #pragma unroll
    for (int p = 0; p < 8; ++p)
      s += cp[p * CTXS + 4096 + t] + cp[p * CTXS + 4160 + t];
    #pragma unroll
    for (int j = 0; j < NMEM; ++j) s += emk[t * 4 + j];
    sd[t] = s;
  }
  __syncthreads();
  u16* ct = ctxTb + (size_t)(g * NH + h) * 4096;
  #pragma unroll
  for (int i = 0; i < 16; ++i) {
    int idx = t + 256 * i;
    int d = idx >> 6, e = idx & 63;
    float v = 0.f;
    #pragma unroll
    for (int p = 0; p < 8; ++p) v += cp[p * CTXS + idx];
    #pragma unroll
    for (int j = 0; j < NMEM; ++j) v += emk[d * 4 + j] * mv[e * 4 + j];
    ct[e * 64 + d] = f2b(v / sd[d]);           // transposed, bf16
  }
}

// ---------------- fused Q-GEMM + q-softmax + PV -> attnT[g][n][hid] bf16 ----------------
__global__ __launch_bounds__(256) void k_qpv(const u16* __restrict__ Wq,
                                             const u16* __restrict__ XT,
                                             const u16* __restrict__ ctxTb,
                                             u16* __restrict__ attnT) {
  constexpr int BK = 32;
  __shared__ __align__(16) u16 smem[24576];    // 48KB
  u16* Ws = smem;                               // [0, 8KB)
  u16* Xs = smem + 4096;                        // [8KB, 16KB)
  u16* cl = smem + 16384;                       // ctxT staging [32KB,48KB)

  int cpx = gridDim.x >> 3;                    // nwg = 4hh*32nc*G, %8==0
  int bid = blockIdx.x;
  int L = (bid & 7) * cpx + (bid >> 3);
  int hh = L & 3, rest = L >> 2;
  int nc = rest & 31, g = rest >> 5;
  int t = threadIdx.x, wave = t >> 6, lane = t & 63;
  int wm = wave >> 1, wn = wave & 1;
  int kg = lane >> 4, lr = lane & 15;

  {
    const u16* cg = ctxTb + (size_t)(g * NH + hh * 2) * 4096;
    #pragma unroll
    for (int i = 0; i < 4; ++i) {
      int id = t + 256 * i;
      int r = id >> 3, c = id & 7;
      *(bf16x8*)(cl + (r >> 6) * 4096 + (r & 63) * 64 + ((c ^ (r & 7)) * 8)) =
          *(const bf16x8*)(cg + id * 8);
    }
  }

  const u16* Ag = Wq + (size_t)(hh * 128) * C_;
  const u16* Bg = XT + ((size_t)g * N_ + nc * 128) * C_;
  int rloc = lane >> 2;
  int cswz = (lane & 3) ^ (rloc & 3);

  f32x4 acc[4][4];
  #pragma unroll
  for (int i = 0; i < 4; ++i)
    #pragma unroll
    for (int j = 0; j < 4; ++j) acc[i][j] = (f32x4)0.f;

  for (int k0 = 0; k0 < C_; k0 += BK) {
    #pragma unroll
    for (int q = 0; q < 2; ++q) {
      int r = wave * 32 + q * 16 + rloc;
      gld_lds16(Ag + (size_t)r * C_ + k0 + cswz * 8, Ws + (wave * 32 + q * 16) * 32);
      gld_lds16(Bg + (size_t)r * C_ + k0 + cswz * 8, Xs + (wave * 32 + q * 16) * 32);
    }
    __syncthreads();
    bf16x8 a[4], bv[4];
    #pragma unroll
    for (int mf = 0; mf < 4; ++mf) {
      int r = wm * 64 + mf * 16 + lr;
      a[mf] = *(const bf16x8*)(Ws + r * 32 + ((kg ^ (r & 3)) * 8));
    }
    #pragma unroll
    for (int nf = 0; nf < 4; ++nf) {
      int r = wn * 64 + nf * 16 + lr;
      bv[nf] = *(const bf16x8*)(Xs + r * 32 + ((kg ^ (r & 3)) * 8));
    }
    #pragma unroll
    for (int mf = 0; mf < 4; ++mf)
      #pragma unroll
      for (int nf = 0; nf < 4; ++nf)
        acc[mf][nf] = __builtin_amdgcn_mfma_f32_16x16x32_bf16(a[mf], bv[nf], acc[mf][nf], 0, 0, 0);
    __syncthreads();
  }

  // ---- phase B: softmax over d per column (wave-local rows = one head) ----
  float colsum[4];
  #pragma unroll
  for (int nf = 0; nf < 4; ++nf) {
    float s = 0.f;
    #pragma unroll
    for (int mf = 0; mf < 4; ++mf)
      #pragma unroll
      for (int j = 0; j < 4; ++j) {
        float e = __expf(acc[mf][nf][j]);
        acc[mf][nf][j] = e;
        s += e;
      }
    colsum[nf] = s;
  }
  #pragma unroll
  for (int nf = 0; nf < 4; ++nf) {
    colsum[nf] += __shfl_xor(colsum[nf], 16);
    colsum[nf] += __shfl_xor(colsum[nf], 32);
  }
  u16* qh = smem + wm * 8192;
  #pragma unroll
  for (int nf = 0; nf < 4; ++nf) {
    float invs = 0.125f / colsum[nf];
    int n = wn * 64 + nf * 16 + lr;
    #pragma unroll
    for (int mf = 0; mf < 4; ++mf)
      #pragma unroll
      for (int jp = 0; jp < 2; ++jp) {
        int d0 = mf * 16 + kg * 4 + jp * 2;
        u16 lo = f2b(acc[mf][nf][jp * 2] * invs);
        u16 hi = f2b(acc[mf][nf][jp * 2 + 1] * invs);
        unsigned pk = (unsigned)lo | ((unsigned)hi << 16);
        int idx = n * 64 + (((d0 >> 3) ^ (n & 7)) * 8) + (d0 & 7);
        *(unsigned*)(qh + idx) = pk;
      }
  }
  __syncthreads();

  // ---- phase C: PV MFMA ----
  int hcl = wave >> 1, nh2 = wave & 1;
  const u16* qh2 = smem + hcl * 8192;
  const u16* clh = cl + hcl * 4096;
  f32x4 acc2[4][4];
  #pragma unroll
  for (int i = 0; i < 4; ++i)
    #pragma unroll
    for (int j = 0; j < 4; ++j) acc2[i][j] = (f32x4)0.f;

  #pragma unroll
  for (int kk = 0; kk < 2; ++kk) {
    int c = kk * 4 + kg;
    bf16x8 a2[4], b2[4];
    #pragma unroll
    for (int mf = 0; mf < 4; ++mf) {
      int rn = nh2 * 64 + mf * 16 + lr;
      a2[mf] = *(const bf16x8*)(qh2 + rn * 64 + ((c ^ (rn & 7)) * 8));
    }
    #pragma unroll
    for (int nf = 0; nf < 4; ++nf) {
      int re = nf * 16 + lr;
      b2[nf] = *(const bf16x8*)(clh + re * 64 + ((c ^ (re & 7)) * 8));
    }
    #pragma unroll
    for (int mf = 0; mf < 4; ++mf)
      #pragma unroll
      for (int nf = 0; nf < 4; ++nf)
        acc2[mf][nf] = __builtin_amdgcn_mfma_f32_16x16x32_bf16(a2[mf], b2[nf], acc2[mf][nf], 0, 0, 0);
  }

  int h = hh * 2 + hcl;
  u16* op = attnT + ((size_t)g * N_ + nc * 128) * HID + h * 64;
  #pragma unroll
  for (int mf = 0; mf < 4; ++mf)
    #pragma unroll
    for (int nf = 0; nf < 4; ++nf)
      #pragma unroll
      for (int j = 0; j < 4; ++j) {
        int n = nh2 * 64 + mf * 16 + kg * 4 + j;
        int e = nf * 16 + lr;
        op[(size_t)n * HID + e] = f2b(acc2[mf][nf][j]);
      }
}

// ---------------- out-proj GEMM + bias + fused rmsnorm2, BN=128 ----------------
__global__ __launch_bounds__(256) void k_out(const u16* __restrict__ Wb,
                                             const u16* __restrict__ AT,
                                             const float* __restrict__ bias,
                                             const float* __restrict__ g2,
                                             float* __restrict__ out) {
  constexpr int BN = 128, BK = 32;
  __shared__ __align__(16) u16 As[256 * BK];   // 16KB
  __shared__ __align__(16) u16 Bs[BN * BK];    // 8KB
  __shared__ float part[4][BN];                // 2KB
  int g  = blockIdx.y;
  int n0 = blockIdx.x * BN;
  int t = threadIdx.x, wave = t >> 6, lane = t & 63;
  int kg = lane >> 4, lr = lane & 15;

  const u16* Bg = AT + ((size_t)g * N_ + n0) * HID;

  int rloc = lane >> 2;
  int cswz = (lane & 3) ^ (rloc & 3);

  f32x4 acc[4][8];
  #pragma unroll
  for (int i = 0; i < 4; ++i)
    #pragma unroll
    for (int j = 0; j < 8; ++j) acc[i][j] = (f32x4)0.f;

  for (int k0 = 0; k0 < HID; k0 += BK) {
    #pragma unroll
    for (int q = 0; q < 4; ++q) {
      int r = wave * 64 + q * 16 + rloc;
      gld_lds16(Wb + (size_t)r * HID + k0 + cswz * 8, As + (wave * 64 + q * 16) * 32);
    }
    #pragma unroll
    for (int q = 0; q < 2; ++q) {
      int r = wave * 32 + q * 16 + rloc;
      gld_lds16(Bg + (size_t)r * HID + k0 + cswz * 8, Bs + (wave * 32 + q * 16) * 32);
    }
    __syncthreads();
    bf16x8 a[4], bv[8];
    #pragma unroll
    for (int mf = 0; mf < 4; ++mf) {
      int r = wave * 64 + mf * 16 + lr;
      a[mf] = *(const bf16x8*)(As + r * 32 + ((kg ^ (r & 3)) * 8));
    }
    #pragma unroll
    for (int nf = 0; nf < 8; ++nf) {
      int r = nf * 16 + lr;
      bv[nf] = *(const bf16x8*)(Bs + r * 32 + ((kg ^ (r & 3)) * 8));
    }
    #pragma unroll
    for (int mf = 0; mf < 4; ++mf)
      #pragma unroll
      for (int nf = 0; nf < 8; ++nf)
        acc[mf][nf] = __builtin_amdgcn_mfma_f32_16x16x32_bf16(a[mf], bv[nf], acc[mf][nf], 0, 0, 0);
    __syncthreads();
  }
  float colsq[8] = {0.f, 0.f, 0.f, 0.f, 0.f, 0.f, 0.f, 0.f};
  #pragma unroll
  for (int mf = 0; mf < 4; ++mf)
    #pragma unroll
    for (int j = 0; j < 4; ++j) {
      int row = wave * 64 + mf * 16 + kg * 4 + j;
      float bs = bias[row];
      #pragma unroll
      for (int nf = 0; nf < 8; ++nf) {
        float v = acc[mf][nf][j] + bs;
        acc[mf][nf][j] = v;
        colsq[nf] += v * v;
      }
    }
  #pragma unroll
  for (int nf = 0; nf < 8; ++nf) {
    colsq[nf] += __shfl_xor(colsq[nf], 16);
    colsq[nf] += __shfl_xor(colsq[nf], 32);
  }
  if (kg == 0) {
    #pragma unroll
    for (int nf = 0; nf < 8; ++nf) part[wave][nf * 16 + lr] = colsq[nf];
  }
  __syncthreads();
  float* og = out + (size_t)g * C_ * N_ + n0;
  #pragma unroll
  for (int nf = 0; nf < 8; ++nf) {
    int col = nf * 16 + lr;
    float tot = part[0][col] + part[1][col] + part[2][col] + part[3][col];
    float invn = 16.0f / fmaxf(sqrtf(tot), 1e-12f);
    #pragma unroll
    for (int mf = 0; mf < 4; ++mf)
      #pragma unroll
      for (int j = 0; j < 4; ++j) {
        int row = wave * 64 + mf * 16 + kg * 4 + j;
        og[(size_t)row * N_ + col] = acc[mf][nf][j] * invn * g2[row];
      }
  }
}

extern "C" void kernel_launch(void* const* d_in, const int* in_sizes, int n_in,
                              void* d_out, int out_size, void* d_ws, size_t ws_size,
                              hipStream_t stream) {
  (void)in_sizes; (void)n_in; (void)out_size;
  const float* x      = (const float*)d_in[0];
  const float* gain1  = (const float*)d_in[1];
  const float* w_qkv  = (const float*)d_in[2];
  const float* mem_kv = (const float*)d_in[3];
  const float* w_out  = (const float*)d_in[4];
  const float* b_out  = (const float*)d_in[5];
  const float* gain2  = (const float*)d_in[6];
  float* out = (float*)d_out;

  char* ws = (char*)d_ws;
  u16* wqkvb = (u16*)ws;                         // 786,432 B
  u16* woutb = (u16*)(ws + 786432);              // 262,144 B
  size_t shared_b = 1048576;

  const size_t xbT_b   = (size_t)N_ * C_ * 2;          //  2 MiB
  const size_t attnT_b = (size_t)HID * N_ * 2;         //  4 MiB
  const size_t ctxp_b  = (size_t)NH * 8 * CTXS * 4;    // ~1.03 MiB
  const size_t ctxT_b  = (size_t)NH * 4096 * 2;        // 64 KiB
  const size_t per_b   = xbT_b + attnT_b + ctxp_b + ctxT_b;

  int G = 16;
  while (G > 1 && shared_b + (size_t)G * per_b > ws_size) G >>= 1;

  char* base = ws + shared_b;
  u16*   xbT   = (u16*)base;
  u16*   attnT = (u16*)(base + (size_t)G * xbT_b);
  float* ctxp  = (float*)(base + (size_t)G * (xbT_b + attnT_b));
  u16*   ctxTb = (u16*)(base + (size_t)G * (xbT_b + attnT_b + ctxp_b));

  k_cvtw<<<256, 256, 0, stream>>>(w_qkv, w_out, wqkvb, woutb);

  for (int b0 = 0; b0 < B_; b0 += G) {
    const float* xc = x + (size_t)b0 * C_ * N_;
    float*       oc = out + (size_t)b0 * C_ * N_;
    k_rms1  <<<dim3(N_ / 256, G),  256, 0, stream>>>(xc, gain1, xbT);
    k_kvctx <<<dim3(64 * G),       256, 0, stream>>>(wqkvb, xbT, ctxp);
    k_cfin  <<<dim3(NH, G),        256, 0, stream>>>(ctxp, mem_kv, ctxTb);
    k_qpv   <<<dim3(4 * 32 * G),   256, 0, stream>>>(wqkvb, xbT, ctxTb, attnT);
    k_out   <<<dim3(N_ / 128, G),  256, 0, stream>>>(woutb, attnT, b_out, gain2, oc);
  }
}